// Round 2
// baseline (1222.683 us; speedup 1.0000x reference)
//
#include <hip/hip_runtime.h>
#include <cstddef>
#include <cstdint>

// ---------------------------------------------------------------- bf16 helpers (fp32 accumulate everywhere)
__device__ __forceinline__ float bf2f(unsigned int u16) {
    union { unsigned int i; float f; } v; v.i = u16 << 16; return v.f;
}
__device__ __forceinline__ unsigned short f2bf(float f) {
    union { float f; unsigned int i; } v; v.f = f;
    unsigned int x = v.i;
    unsigned int r = (x + 0x7FFFu + ((x >> 16) & 1u)) >> 16;   // round-nearest-even
    return (unsigned short)r;
}
__device__ __forceinline__ float geluf(float x) {
    return 0.5f * x * (1.0f + erff(x * 0.70710678118654752f));
}
__device__ __forceinline__ void fma4(float4& d, float a, const float4& b) {
    d.x += a * b.x; d.y += a * b.y; d.z += a * b.z; d.w += a * b.w;
}

// ---------------------------------------------------------------- zero fill (avoid memset during graph capture)
__global__ void k_zero(int* __restrict__ p, int n) {
    int i = blockIdx.x * 256 + threadIdx.x;
    if (i < n) p[i] = 0;
}

// ---------------------------------------------------------------- prep: fold a_rel (+p_rel/sqrt(D)) and m_rel into K/V weights
// Wkv[lt][k][c] : c in [0,256), 0..127 = k' cols, 128..255 = v' cols. k==128 row -> Bkv bias.
__global__ void k_prep(const float* __restrict__ kw, const float* __restrict__ kb,
                       const float* __restrict__ vw, const float* __restrict__ vb,
                       const float* __restrict__ arel, const float* __restrict__ mrel,
                       const float* __restrict__ prel,
                       float* __restrict__ Wkv, float* __restrict__ Bkv) {
    int lt = blockIdx.y;                       // l*2+t, 0..3
    int tid = blockIdx.x * 256 + threadIdx.x;  // over 129*256
    if (tid >= 129 * 256) return;
    int k = tid >> 8;
    int c = tid & 255;
    int sec = c >> 7, cc = c & 127, h = cc >> 5, e = cc & 31;
    const float* Wsrc = sec ? vw : kw;
    const float* Bsrc = sec ? vb : kb;
    const float* R    = sec ? mrel : arel;
    float scale = sec ? 1.0f : prel[lt * 4 + h] * 0.17677669529663687f;  // p/sqrt(32)
    const float* rp = R + (size_t)(lt * 4 + h) * 1024 + e;               // R[lt,h,d,e], stride 32 over d
    const float* wp = (k < 128) ? (Wsrc + (size_t)lt * 16384 + (size_t)k * 128 + h * 32)
                                : (Bsrc + lt * 128 + h * 32);
    float s = 0.f;
    #pragma unroll 8
    for (int d = 0; d < 32; ++d) s += wp[d] * rp[(size_t)d * 32];
    s *= scale;
    if (k < 128) Wkv[(size_t)lt * 128 * 256 + (size_t)k * 256 + c] = s;
    else         Bkv[lt * 256 + c] = s;
}

// ---------------------------------------------------------------- GEMM: C_bf16[N,cols] = act(A[N,128]) @ W_f32[128,cols] + b, fused epilogues
// A row stride fixed at 128. Column block = 128 wide (blockIdx.y selects).
template<int TM, bool ABF16, bool GELU_IN, bool RELU_OUT, bool SKIP>
__global__ __launch_bounds__(256) void k_gemm(
    const void* __restrict__ Av, const float* __restrict__ W,
    const float* __restrict__ bias, unsigned short* __restrict__ C,
    int N, int ldW, int ldC,
    const unsigned short* __restrict__ Xold, const float* __restrict__ skipPtr) {
    constexpr int KC = 32;
    constexpr int RQ = TM / 64;
    __shared__ float As[KC][TM + 4];
    __shared__ float Ws[KC][128];
    const int rowBase = blockIdx.x * TM;
    const int colBase = blockIdx.y * 128;
    const int t = threadIdx.x;
    const int tx = t & 15, ty = t >> 4;

    float4 acc[RQ][2][4];
    #pragma unroll
    for (int i = 0; i < RQ; ++i)
        #pragma unroll
        for (int j = 0; j < 2; ++j)
            #pragma unroll
            for (int r = 0; r < 4; ++r) acc[i][j][r] = make_float4(0.f, 0.f, 0.f, 0.f);

    for (int k0 = 0; k0 < 128; k0 += KC) {
        if (ABF16) {
            const unsigned short* A = (const unsigned short*)Av;
            constexpr int LOADS = TM * KC / (8 * 256);   // 8 bf16 per thread per load
            #pragma unroll
            for (int i = 0; i < LOADS; ++i) {
                int f = t + i * 256;
                int row = f >> 2, kg = f & 3;
                int gr = rowBase + row; if (gr >= N) gr = N - 1;
                uint4 raw = *(const uint4*)(A + (size_t)gr * 128 + k0 + kg * 8);
                float e[8];
                e[0] = bf2f(raw.x & 0xFFFF); e[1] = bf2f(raw.x >> 16);
                e[2] = bf2f(raw.y & 0xFFFF); e[3] = bf2f(raw.y >> 16);
                e[4] = bf2f(raw.z & 0xFFFF); e[5] = bf2f(raw.z >> 16);
                e[6] = bf2f(raw.w & 0xFFFF); e[7] = bf2f(raw.w >> 16);
                #pragma unroll
                for (int j = 0; j < 8; ++j) {
                    float vv = GELU_IN ? geluf(e[j]) : e[j];
                    As[kg * 8 + j][row] = vv;
                }
            }
        } else {
            const float* A = (const float*)Av;
            constexpr int AF = TM * KC / (4 * 256);
            #pragma unroll
            for (int i = 0; i < AF; ++i) {
                int f = t + i * 256;
                int row = f >> 3, kq = f & 7;
                int gr = rowBase + row; if (gr >= N) gr = N - 1;
                float4 v = *(const float4*)(A + (size_t)gr * 128 + k0 + kq * 4);
                if (GELU_IN) { v.x = geluf(v.x); v.y = geluf(v.y); v.z = geluf(v.z); v.w = geluf(v.w); }
                As[kq * 4 + 0][row] = v.x;
                As[kq * 4 + 1][row] = v.y;
                As[kq * 4 + 2][row] = v.z;
                As[kq * 4 + 3][row] = v.w;
            }
        }
        #pragma unroll
        for (int i = 0; i < 4; ++i) {
            int f = t + i * 256;
            int kk = f >> 5, cq = f & 31;
            *(float4*)&Ws[kk][cq * 4] =
                *(const float4*)(W + (size_t)(k0 + kk) * ldW + colBase + cq * 4);
        }
        __syncthreads();
        #pragma unroll
        for (int k = 0; k < KC; ++k) {
            float4 av[RQ], wv[2];
            #pragma unroll
            for (int i = 0; i < RQ; ++i) av[i] = *(const float4*)&As[k][i * 64 + ty * 4];
            #pragma unroll
            for (int j = 0; j < 2; ++j) wv[j] = *(const float4*)&Ws[k][j * 64 + tx * 4];
            #pragma unroll
            for (int i = 0; i < RQ; ++i)
                #pragma unroll
                for (int j = 0; j < 2; ++j) {
                    fma4(acc[i][j][0], av[i].x, wv[j]);
                    fma4(acc[i][j][1], av[i].y, wv[j]);
                    fma4(acc[i][j][2], av[i].z, wv[j]);
                    fma4(acc[i][j][3], av[i].w, wv[j]);
                }
        }
        __syncthreads();
    }

    float g = 0.f;
    if (SKIP) g = 1.f / (1.f + expf(-skipPtr[0]));
    #pragma unroll
    for (int i = 0; i < RQ; ++i) {
        #pragma unroll
        for (int r = 0; r < 4; ++r) {
            int row = rowBase + i * 64 + ty * 4 + r;
            if (row < N) {
                #pragma unroll
                for (int j = 0; j < 2; ++j) {
                    int col = colBase + j * 64 + tx * 4;
                    float4 v = acc[i][j][r];
                    float4 b4 = *(const float4*)(bias + col);
                    v.x += b4.x; v.y += b4.y; v.z += b4.z; v.w += b4.w;
                    if (RELU_OUT) {
                        v.x = fmaxf(v.x, 0.f); v.y = fmaxf(v.y, 0.f);
                        v.z = fmaxf(v.z, 0.f); v.w = fmaxf(v.w, 0.f);
                    }
                    if (SKIP) {
                        ushort4 xo = *(const ushort4*)(Xold + (size_t)row * 128 + col);
                        float og = 1.f - g;
                        v.x = g * v.x + og * bf2f(xo.x);
                        v.y = g * v.y + og * bf2f(xo.y);
                        v.z = g * v.z + og * bf2f(xo.z);
                        v.w = g * v.w + og * bf2f(xo.w);
                    }
                    ushort4 o;
                    o.x = f2bf(v.x); o.y = f2bf(v.y); o.z = f2bf(v.z); o.w = f2bf(v.w);
                    *(ushort4*)(C + (size_t)row * ldC + col) = o;
                }
            }
        }
    }
}

// ---------------------------------------------------------------- CSR build
__global__ void k_hist(const int* __restrict__ dst, int E, int* __restrict__ deg) {
    int e = blockIdx.x * 256 + threadIdx.x;
    if (e < E) atomicAdd(&deg[dst[e]], 1);
}
__global__ void k_scan_block(const int* __restrict__ deg, int n, int* __restrict__ off,
                             int* __restrict__ partials) {
    __shared__ int s[256];
    int i = blockIdx.x * 256 + threadIdx.x;
    s[threadIdx.x] = (i < n) ? deg[i] : 0;
    __syncthreads();
    for (int d = 1; d < 256; d <<= 1) {
        int t = (threadIdx.x >= d) ? s[threadIdx.x - d] : 0;
        __syncthreads();
        s[threadIdx.x] += t;
        __syncthreads();
    }
    if (i < n) off[i + 1] = s[threadIdx.x];
    if (threadIdx.x == 255) partials[blockIdx.x] = s[255];
}
__global__ void k_scan_partials(int* __restrict__ partials, int nb) {
    __shared__ int s[256];
    s[threadIdx.x] = (threadIdx.x < nb) ? partials[threadIdx.x] : 0;
    __syncthreads();
    for (int d = 1; d < 256; d <<= 1) {
        int t = (threadIdx.x >= d) ? s[threadIdx.x - d] : 0;
        __syncthreads();
        s[threadIdx.x] += t;
        __syncthreads();
    }
    if (threadIdx.x < nb) partials[threadIdx.x] = s[threadIdx.x];
}
__global__ void k_scan_add(int* __restrict__ off, const int* __restrict__ partials, int n) {
    int i = blockIdx.x * 256 + threadIdx.x;
    if (i == 0) off[0] = 0;
    if (i < n) {
        int b = i >> 8;
        if (b > 0) off[i + 1] += partials[b - 1];
    }
}
__global__ void k_scatter(const int* __restrict__ edges, int E, const int* __restrict__ off,
                          int* __restrict__ cursor, int* __restrict__ csrc, int* __restrict__ cdst) {
    int e = blockIdx.x * 256 + threadIdx.x;
    if (e < E) {
        int d = edges[E + e];
        int pos = off[d] + atomicAdd(&cursor[d], 1);
        csrc[pos] = edges[e];
        cdst[pos] = d;
    }
}

// ---------------------------------------------------------------- attention: alpha per (edge, head). Q:[Nd,128] bf16, KV:[Ns,256] bf16 (k' cols 0..127)
__global__ void k_alpha(const unsigned short* __restrict__ Q, const unsigned short* __restrict__ KV,
                        const int* __restrict__ csrc, const int* __restrict__ cdst,
                        int E, float* __restrict__ alphaS) {
    int tid = blockIdx.x * 256 + threadIdx.x;
    int i = tid >> 2, h = tid & 3;
    if (i >= E) return;
    const uint4* q = (const uint4*)(Q + (size_t)cdst[i] * 128 + h * 32);
    const uint4* k = (const uint4*)(KV + (size_t)csrc[i] * 256 + h * 32);
    float s = 0.f;
    #pragma unroll
    for (int j = 0; j < 4; ++j) {
        uint4 a = q[j], b = k[j];
        s += bf2f(a.x & 0xFFFF) * bf2f(b.x & 0xFFFF) + bf2f(a.x >> 16) * bf2f(b.x >> 16);
        s += bf2f(a.y & 0xFFFF) * bf2f(b.y & 0xFFFF) + bf2f(a.y >> 16) * bf2f(b.y >> 16);
        s += bf2f(a.z & 0xFFFF) * bf2f(b.z & 0xFFFF) + bf2f(a.z >> 16) * bf2f(b.z >> 16);
        s += bf2f(a.w & 0xFFFF) * bf2f(b.w & 0xFFFF) + bf2f(a.w >> 16) * bf2f(b.w >> 16);
    }
    alphaS[(size_t)i * 4 + h] = s;
}

// ---------------------------------------------------------------- per-dst online softmax + weighted aggregation (v' = KV cols 128..255)
__global__ __launch_bounds__(256) void k_agg(const unsigned short* __restrict__ KV,
                                             const float* __restrict__ alphaS,
                                             const int* __restrict__ off,
                                             const int* __restrict__ csrc,
                                             unsigned short* __restrict__ out, int n_dst) {
    int dst = blockIdx.x * 4 + (threadIdx.x >> 6);
    int lane = threadIdx.x & 63;
    if (dst >= n_dst) return;
    int s0 = off[dst], s1 = off[dst + 1];
    int h0 = lane >> 5;  // channel c0=lane (head h0), c1=lane+64 (head 2+h0)
    float m0 = -INFINITY, m1 = -INFINITY, d0 = 0.f, d1 = 0.f, a0 = 0.f, a1 = 0.f;
    for (int j = s0; j < s1; ++j) {
        int src = csrc[j];
        float al0 = alphaS[(size_t)j * 4 + h0];
        float al1 = alphaS[(size_t)j * 4 + 2 + h0];
        const unsigned short* vp = KV + (size_t)src * 256 + 128;
        float v0 = bf2f(vp[lane]), v1 = bf2f(vp[lane + 64]);
        float nm0 = fmaxf(m0, al0);
        float sc0 = expf(m0 - nm0);
        float p0 = expf(al0 - nm0);
        d0 = d0 * sc0 + p0; a0 = a0 * sc0 + p0 * v0; m0 = nm0;
        float nm1 = fmaxf(m1, al1);
        float sc1 = expf(m1 - nm1);
        float p1 = expf(al1 - nm1);
        d1 = d1 * sc1 + p1; a1 = a1 * sc1 + p1 * v1; m1 = nm1;
    }
    float r0 = (s1 > s0) ? a0 / d0 : 0.f;
    float r1 = (s1 > s0) ? a1 / d1 : 0.f;
    out[(size_t)dst * 128 + lane] = f2bf(r0);
    out[(size_t)dst * 128 + 64 + lane] = f2bf(r1);
}

// ---------------------------------------------------------------- output head: logits -> softmax -> segment sums
__global__ void k_head(const unsigned short* __restrict__ h2, const float* __restrict__ w2,
                       const float* __restrict__ b2, const int* __restrict__ batch,
                       int N, float* __restrict__ gsum, float* __restrict__ gcnt) {
    int node = blockIdx.x * 256 + threadIdx.x;
    if (node >= N) return;
    const uint4* hp = (const uint4*)(h2 + (size_t)node * 128);
    float l0 = b2[0], l1 = b2[1];
    #pragma unroll
    for (int j = 0; j < 16; ++j) {
        uint4 raw = hp[j];
        float e[8];
        e[0] = bf2f(raw.x & 0xFFFF); e[1] = bf2f(raw.x >> 16);
        e[2] = bf2f(raw.y & 0xFFFF); e[3] = bf2f(raw.y >> 16);
        e[4] = bf2f(raw.z & 0xFFFF); e[5] = bf2f(raw.z >> 16);
        e[6] = bf2f(raw.w & 0xFFFF); e[7] = bf2f(raw.w >> 16);
        int k = j * 8;
        #pragma unroll
        for (int q = 0; q < 8; ++q) {
            l0 += e[q] * w2[(k + q) * 2];
            l1 += e[q] * w2[(k + q) * 2 + 1];
        }
    }
    float m = fmaxf(l0, l1);
    float e0 = expf(l0 - m), e1 = expf(l1 - m);
    float inv = 1.f / (e0 + e1);
    int b = batch[node];
    atomicAdd(&gsum[b * 2 + 0], e0 * inv);
    atomicAdd(&gsum[b * 2 + 1], e1 * inv);
    atomicAdd(&gcnt[b], 1.f);
}
__global__ void k_finalize(const float* __restrict__ gsum, const float* __restrict__ gcnt,
                           float* __restrict__ out, int n) {
    int i = blockIdx.x * 256 + threadIdx.x;
    if (i < n) out[i] = gsum[i] / fmaxf(gcnt[i >> 1], 1.f);
}

// ---------------------------------------------------------------- host
extern "C" void kernel_launch(void* const* d_in, const int* in_sizes, int n_in,
                              void* d_out, int out_size, void* d_ws, size_t ws_size,
                              hipStream_t stream) {
    const float* x_var    = (const float*)d_in[0];
    const float* x_con    = (const float*)d_in[1];
    const float* mlp_in_w = (const float*)d_in[2];
    const float* mlp_in_b = (const float*)d_in[3];
    const float* mow0 = (const float*)d_in[4];
    const float* mob0 = (const float*)d_in[5];
    const float* mow1 = (const float*)d_in[6];
    const float* mob1 = (const float*)d_in[7];
    const float* mow2 = (const float*)d_in[8];
    const float* mob2 = (const float*)d_in[9];
    const float* k_w  = (const float*)d_in[10];
    const float* k_b  = (const float*)d_in[11];
    const float* q_w  = (const float*)d_in[12];
    const float* q_b  = (const float*)d_in[13];
    const float* v_w  = (const float*)d_in[14];
    const float* v_b  = (const float*)d_in[15];
    const float* a_w  = (const float*)d_in[16];
    const float* a_b  = (const float*)d_in[17];
    const float* skipP = (const float*)d_in[18];
    const float* a_rel = (const float*)d_in[19];
    const float* m_rel = (const float*)d_in[20];
    const float* p_rel = (const float*)d_in[21];
    const int* edge_vc = (const int*)d_in[22];
    const int* edge_cv = (const int*)d_in[23];
    const int* batch   = (const int*)d_in[24];

    const int Nv = in_sizes[0] / 128;
    const int Nc = in_sizes[1] / 128;
    const int E  = in_sizes[22] / 2;
    const int G  = out_size / 2;
    const int nmax = Nv > Nc ? Nv : Nc;

    // ---- workspace layout (bf16 intermediates; fp32 alphas/weights)
    float* fbase = (float*)d_ws;
    size_t fo = 0;
    auto falloc = [&](size_t n) { float* p = fbase + fo; fo += n; return p; };
    float* alphaS = falloc((size_t)E * 4);
    float* Wkv    = falloc((size_t)4 * 128 * 256);
    float* Bkv    = falloc(4 * 256);
    float* gsum   = falloc((size_t)G * 2);
    float* gcnt   = falloc((size_t)G);

    unsigned short* bbase = (unsigned short*)(fbase + fo);
    size_t bo = 0;
    auto balloc = [&](size_t n) { unsigned short* p = bbase + bo; bo += n; return p; };
    unsigned short* cur0  = balloc((size_t)Nv * 128);
    unsigned short* cur1  = balloc((size_t)Nc * 128);
    unsigned short* Qbuf  = balloc((size_t)nmax * 128);
    unsigned short* KVbuf = balloc((size_t)nmax * 256);
    unsigned short* agg0  = balloc((size_t)Nv * 128);
    unsigned short* agg1  = balloc((size_t)Nc * 128);
    if (bo & 1) ++bo;

    int* ibase = (int*)(bbase + bo);
    size_t io = 0;
    auto ialloc = [&](size_t n) { int* p = ibase + io; io += n; return p; };
    int* offVC = ialloc((size_t)Nc + 1);
    int* srcVC = ialloc(E);
    int* dstVC = ialloc(E);
    int* offCV = ialloc((size_t)Nv + 1);
    int* srcCV = ialloc(E);
    int* dstCV = ialloc(E);
    int* deg      = ialloc(nmax);
    int* cursor   = ialloc(nmax);
    int* partials = ialloc(256);

    size_t need = (char*)(ibase + io) - (char*)d_ws;
    if (need > ws_size) return;   // diagnostic: clean failure instead of OOB fault

    const int eb = (E + 255) / 256;

    // ---- CSR builds
    auto buildCSR = [&](const int* edges, int n_dst, int* offA, int* csrcA, int* cdstA) {
        int nzb = (n_dst + 255) / 256;
        k_zero<<<nzb, 256, 0, stream>>>(deg, n_dst);
        k_hist<<<eb, 256, 0, stream>>>(edges + E, E, deg);
        k_scan_block<<<nzb, 256, 0, stream>>>(deg, n_dst, offA, partials);
        k_scan_partials<<<1, 256, 0, stream>>>(partials, nzb);
        k_scan_add<<<nzb, 256, 0, stream>>>(offA, partials, n_dst);
        k_zero<<<nzb, 256, 0, stream>>>(cursor, n_dst);
        k_scatter<<<eb, 256, 0, stream>>>(edges, E, offA, cursor, csrcA, cdstA);
    };
    buildCSR(edge_vc, Nc, offVC, srcVC, dstVC);
    buildCSR(edge_cv, Nv, offCV, srcCV, dstCV);

    // ---- fold rel transforms into K/V weights
    k_prep<<<dim3((129 * 256 + 255) / 256, 4), 256, 0, stream>>>(
        k_w, k_b, v_w, v_b, a_rel, m_rel, p_rel, Wkv, Bkv);

    // ---- GEMM wrappers (A row stride 128; C bf16)
    auto g_f32_relu = [&](const float* A, const float* W, const float* b, unsigned short* C, int N) {
        k_gemm<64, false, false, true, false><<<dim3((N + 63) / 64, 1), 256, 0, stream>>>(
            A, W, b, C, N, 128, 128, nullptr, nullptr);
    };
    auto g_bf_relu = [&](const unsigned short* A, const float* W, const float* b, unsigned short* C, int N) {
        k_gemm<64, true, false, true, false><<<dim3((N + 63) / 64, 1), 256, 0, stream>>>(
            A, W, b, C, N, 128, 128, nullptr, nullptr);
    };
    auto g_bf_plain = [&](const unsigned short* A, const float* W, const float* b, unsigned short* C, int N) {
        k_gemm<64, true, false, false, false><<<dim3((N + 63) / 64, 1), 256, 0, stream>>>(
            A, W, b, C, N, 128, 128, nullptr, nullptr);
    };
    auto g_bf_kv = [&](const unsigned short* A, const float* W, const float* b, unsigned short* C, int N) {
        k_gemm<128, true, false, false, false><<<dim3((N + 127) / 128, 2), 256, 0, stream>>>(
            A, W, b, C, N, 256, 256, nullptr, nullptr);
    };
    auto g_alin = [&](const unsigned short* A, const float* W, const float* b, unsigned short* C, int N,
                      const unsigned short* xold, const float* sp) {
        k_gemm<64, true, true, false, true><<<dim3((N + 63) / 64, 1), 256, 0, stream>>>(
            A, W, b, C, N, 128, 128, xold, sp);
    };

    // ---- input MLPs (temp buffers reuse Qbuf/KVbuf)
    g_f32_relu(x_var, mlp_in_w + (size_t)0 * 16384, mlp_in_b + 0,   Qbuf,  Nv);
    g_bf_relu (Qbuf,  mlp_in_w + (size_t)1 * 16384, mlp_in_b + 128, KVbuf, Nv);
    g_bf_plain(KVbuf, mlp_in_w + (size_t)2 * 16384, mlp_in_b + 256, cur0,  Nv);
    g_f32_relu(x_con, mlp_in_w + (size_t)3 * 16384, mlp_in_b + 384, Qbuf,  Nc);
    g_bf_relu (Qbuf,  mlp_in_w + (size_t)4 * 16384, mlp_in_b + 512, KVbuf, Nc);
    g_bf_plain(KVbuf, mlp_in_w + (size_t)5 * 16384, mlp_in_b + 640, cur1,  Nc);

    // ---- HGT layers (edge types processed sequentially; Q/KV buffers shared)
    const int ab = (E * 4 + 255) / 256;
    for (int l = 0; l < 2; ++l) {
        int lt0 = l * 2 + 0, lt1 = l * 2 + 1;
        // pass 0: var -> con (q of con, k'/v' of var)
        g_bf_plain(cur1, q_w + (size_t)lt1 * 16384, q_b + lt1 * 128, Qbuf, Nc);
        g_bf_kv   (cur0, Wkv + (size_t)lt0 * 32768, Bkv + lt0 * 256, KVbuf, Nv);
        k_alpha<<<ab, 256, 0, stream>>>(Qbuf, KVbuf, srcVC, dstVC, E, alphaS);
        k_agg<<<(Nc + 3) / 4, 256, 0, stream>>>(KVbuf, alphaS, offVC, srcVC, agg1, Nc);
        // pass 1: con -> var (q of var, k'/v' of con)
        g_bf_plain(cur0, q_w + (size_t)lt0 * 16384, q_b + lt0 * 128, Qbuf, Nv);
        g_bf_kv   (cur1, Wkv + (size_t)lt1 * 32768, Bkv + lt1 * 256, KVbuf, Nc);
        k_alpha<<<ab, 256, 0, stream>>>(Qbuf, KVbuf, srcCV, dstCV, E, alphaS);
        k_agg<<<(Nv + 3) / 4, 256, 0, stream>>>(KVbuf, alphaS, offCV, srcCV, agg0, Nv);
        // gated updates, in-place into cur
        g_alin(agg0, a_w + (size_t)lt0 * 16384, a_b + lt0 * 128, cur0, Nv, cur0, skipP + lt0);
        g_alin(agg1, a_w + (size_t)lt1 * 16384, a_b + lt1 * 128, cur1, Nc, cur1, skipP + lt1);
    }

    // ---- output head (reuse Qbuf/KVbuf as h1/h2)
    g_bf_relu(cur0, mow0, mob0, Qbuf,  Nv);
    g_bf_relu(Qbuf, mow1, mob1, KVbuf, Nv);
    k_zero<<<(G * 3 + 255) / 256, 256, 0, stream>>>((int*)gsum, G * 3);  // gsum (G*2) + gcnt (G) contiguous
    k_head<<<(Nv + 255) / 256, 256, 0, stream>>>(KVbuf, mow2, mob2, batch, Nv, gsum, gcnt);
    k_finalize<<<(G * 2 + 255) / 256, 256, 0, stream>>>(gsum, gcnt, (float*)d_out, G * 2);
}

// Round 3
// 864.699 us; speedup vs baseline: 1.4140x; 1.4140x over previous
//
#include <hip/hip_runtime.h>
#include <cstddef>
#include <cstdint>

typedef __attribute__((ext_vector_type(8))) short short8;
typedef __attribute__((ext_vector_type(4))) float float4v;

// ---------------------------------------------------------------- bf16 helpers (fp32 accumulate everywhere)
__device__ __forceinline__ float bf2f(unsigned int u16) {
    union { unsigned int i; float f; } v; v.i = u16 << 16; return v.f;
}
__device__ __forceinline__ float bf2f_lo(unsigned int u) {
    union { unsigned int i; float f; } v; v.i = u << 16; return v.f;
}
__device__ __forceinline__ float bf2f_hi(unsigned int u) {
    union { unsigned int i; float f; } v; v.i = u & 0xFFFF0000u; return v.f;
}
__device__ __forceinline__ unsigned short f2bf(float f) {
    union { float f; unsigned int i; } v; v.f = f;
    unsigned int x = v.i;
    unsigned int r = (x + 0x7FFFu + ((x >> 16) & 1u)) >> 16;   // round-nearest-even
    return (unsigned short)r;
}
__device__ __forceinline__ float geluf(float x) {
    return 0.5f * x * (1.0f + erff(x * 0.70710678118654752f));
}

// ---------------------------------------------------------------- zero fill
__global__ void k_zero(int* __restrict__ p, int n) {
    int i = blockIdx.x * 256 + threadIdx.x;
    if (i < n) p[i] = 0;
}

// ---------------------------------------------------------------- cast fp32 -> bf16 (x4 per thread)
__global__ void k_cast(const float* __restrict__ x, unsigned short* __restrict__ o, int n4) {
    int i = blockIdx.x * 256 + threadIdx.x;
    if (i < n4) {
        float4 v = *(const float4*)(x + (size_t)i * 4);
        ushort4 u;
        u.x = f2bf(v.x); u.y = f2bf(v.y); u.z = f2bf(v.z); u.w = f2bf(v.w);
        *(ushort4*)(o + (size_t)i * 4) = u;
    }
}

// ---------------------------------------------------------------- prep: fold a_rel (+p_rel/sqrt(D)) and m_rel into K/V weights (fp32)
// Wkv[lt][k][c] : c in [0,256), 0..127 = k' cols, 128..255 = v' cols. k==128 row -> Bkv bias.
__global__ void k_prep(const float* __restrict__ kw, const float* __restrict__ kb,
                       const float* __restrict__ vw, const float* __restrict__ vb,
                       const float* __restrict__ arel, const float* __restrict__ mrel,
                       const float* __restrict__ prel,
                       float* __restrict__ Wkv, float* __restrict__ Bkv) {
    int lt = blockIdx.y;                       // l*2+t, 0..3
    int tid = blockIdx.x * 256 + threadIdx.x;  // over 129*256
    if (tid >= 129 * 256) return;
    int k = tid >> 8;
    int c = tid & 255;
    int sec = c >> 7, cc = c & 127, h = cc >> 5, e = cc & 31;
    const float* Wsrc = sec ? vw : kw;
    const float* Bsrc = sec ? vb : kb;
    const float* R    = sec ? mrel : arel;
    float scale = sec ? 1.0f : prel[lt * 4 + h] * 0.17677669529663687f;  // p/sqrt(32)
    const float* rp = R + (size_t)(lt * 4 + h) * 1024 + e;               // R[lt,h,d,e], stride 32 over d
    const float* wp = (k < 128) ? (Wsrc + (size_t)lt * 16384 + (size_t)k * 128 + h * 32)
                                : (Bsrc + lt * 128 + h * 32);
    float s = 0.f;
    #pragma unroll 8
    for (int d = 0; d < 32; ++d) s += wp[d] * rp[(size_t)d * 32];
    s *= scale;
    if (k < 128) Wkv[(size_t)lt * 128 * 256 + (size_t)k * 256 + c] = s;
    else         Bkv[lt * 256 + c] = s;
}

// ---------------------------------------------------------------- swizzle all weight units (128x128 fp32) into MFMA B-fragment order (bf16)
// unit layout: out[((s*8+t)*64 + l)*8 + j] = W[k=s*32+(l>>4)*8+j][n=t*16+(l&15)]
__global__ void k_swz(const float* __restrict__ mlp_in_w, const float* __restrict__ q_w,
                      const float* __restrict__ a_w, const float* __restrict__ mow0,
                      const float* __restrict__ mow1, const float* __restrict__ Wkv,
                      unsigned short* __restrict__ Wswz) {
    int idx = blockIdx.y;
    int f = blockIdx.x * 256 + threadIdx.x;  // 16384 per unit
    if (f >= 16384) return;
    int j = f & 7, l = (f >> 3) & 63, t = (f >> 9) & 7, s = f >> 12;
    int k = s * 32 + (l >> 4) * 8 + j;
    int n = t * 16 + (l & 15);
    const float* src; int ld = 128;
    if (idx < 6)        src = mlp_in_w + (size_t)idx * 16384;
    else if (idx < 10)  src = q_w + (size_t)(idx - 6) * 16384;
    else if (idx < 14)  src = a_w + (size_t)(idx - 10) * 16384;
    else if (idx == 14) src = mow0;
    else if (idx == 15) src = mow1;
    else { int u = idx - 16; src = Wkv + (size_t)(u >> 1) * 32768 + (u & 1) * 128; ld = 256; }
    Wswz[(size_t)idx * 16384 + f] = f2bf(src[(size_t)k * ld + n]);
}

// ---------------------------------------------------------------- MFMA GEMM: C_bf16[N, gy*128] = A_bf16[N,128] @ Wunit + bias (+relu | +gated skip)
// One wave computes 16 rows x 128 cols. Barrier-free, LDS-free: A-frags direct from
// global (64B-efficient), B-frags from pre-swizzled L2-hot weights (fully coalesced).
template<bool RELU, bool SKIP>
__global__ __launch_bounds__(256) void k_mfma(
    const unsigned short* __restrict__ A, const unsigned short* __restrict__ Bswz,
    const float* __restrict__ bias, unsigned short* __restrict__ C,
    int N, int ldC, const unsigned short* __restrict__ Xold,
    const float* __restrict__ skipPtr) {
    const int lane = threadIdx.x & 63;
    const int wave = threadIdx.x >> 6;
    const int quad = lane >> 4, mrow = lane & 15;
    const int mbase = blockIdx.x * 64 + wave * 16;
    const int cbase = blockIdx.y * 128;
    const unsigned short* Bu = Bswz + (size_t)blockIdx.y * 16384 + lane * 8;
    int r0 = mbase + mrow; if (r0 >= N) r0 = N - 1;
    const unsigned short* ap = A + (size_t)r0 * 128 + quad * 8;
    float4v acc[8];
    #pragma unroll
    for (int t = 0; t < 8; ++t) acc[t] = (float4v){0.f, 0.f, 0.f, 0.f};
    #pragma unroll
    for (int s = 0; s < 4; ++s) {
        short8 av = *(const short8*)(ap + s * 32);
        #pragma unroll
        for (int t = 0; t < 8; ++t) {
            short8 bv = *(const short8*)(Bu + (s * 8 + t) * 512);
            acc[t] = __builtin_amdgcn_mfma_f32_16x16x32_bf16(av, bv, acc[t], 0, 0, 0);
        }
    }
    float g = 0.f, og = 0.f;
    if (SKIP) { g = 1.f / (1.f + __expf(-skipPtr[0])); og = 1.f - g; }
    #pragma unroll
    for (int t = 0; t < 8; ++t) {
        int col = cbase + t * 16 + mrow;
        float b = bias[col];
        #pragma unroll
        for (int r = 0; r < 4; ++r) {
            int row = mbase + quad * 4 + r;
            if (row < N) {
                float v = acc[t][r] + b;
                if (RELU) v = fmaxf(v, 0.f);
                if (SKIP) v = g * v + og * bf2f(Xold[(size_t)row * ldC + col]);
                C[(size_t)row * ldC + col] = f2bf(v);
            }
        }
    }
}

// ---------------------------------------------------------------- CSR build
__global__ void k_hist(const int* __restrict__ dst, int E, int* __restrict__ deg) {
    int e = blockIdx.x * 256 + threadIdx.x;
    if (e < E) atomicAdd(&deg[dst[e]], 1);
}
__global__ void k_scan_block(const int* __restrict__ deg, int n, int* __restrict__ off,
                             int* __restrict__ partials) {
    __shared__ int s[256];
    int i = blockIdx.x * 256 + threadIdx.x;
    s[threadIdx.x] = (i < n) ? deg[i] : 0;
    __syncthreads();
    for (int d = 1; d < 256; d <<= 1) {
        int t = (threadIdx.x >= d) ? s[threadIdx.x - d] : 0;
        __syncthreads();
        s[threadIdx.x] += t;
        __syncthreads();
    }
    if (i < n) off[i + 1] = s[threadIdx.x];
    if (threadIdx.x == 255) partials[blockIdx.x] = s[255];
}
__global__ void k_scan_partials(int* __restrict__ partials, int nb) {
    __shared__ int s[256];
    s[threadIdx.x] = (threadIdx.x < nb) ? partials[threadIdx.x] : 0;
    __syncthreads();
    for (int d = 1; d < 256; d <<= 1) {
        int t = (threadIdx.x >= d) ? s[threadIdx.x - d] : 0;
        __syncthreads();
        s[threadIdx.x] += t;
        __syncthreads();
    }
    if (threadIdx.x < nb) partials[threadIdx.x] = s[threadIdx.x];
}
__global__ void k_scan_add(int* __restrict__ off, const int* __restrict__ partials, int n) {
    int i = blockIdx.x * 256 + threadIdx.x;
    if (i == 0) off[0] = 0;
    if (i < n) {
        int b = i >> 8;
        if (b > 0) off[i + 1] += partials[b - 1];
    }
}
__global__ void k_scatter(const int* __restrict__ edges, int E, const int* __restrict__ off,
                          int* __restrict__ cursor, int* __restrict__ csrc) {
    int e = blockIdx.x * 256 + threadIdx.x;
    if (e < E) {
        int d = edges[E + e];
        int pos = off[d] + atomicAdd(&cursor[d], 1);
        csrc[pos] = edges[e];
    }
}

// ---------------------------------------------------------------- fused attention: inline q.k' dot (shfl reduce) + online softmax + v' agg (+gelu)
// channel map: lane handles channels 2*lane, 2*lane+1 -> both in head lane>>4.
template<bool GELU_OUT>
__global__ __launch_bounds__(256) void k_agg(
    const unsigned short* __restrict__ Q, const unsigned short* __restrict__ KV,
    const int* __restrict__ off, const int* __restrict__ csrc,
    unsigned short* __restrict__ out, int n_dst) {
    int dst = blockIdx.x * 4 + (threadIdx.x >> 6);
    int lane = threadIdx.x & 63;
    if (dst >= n_dst) return;
    int s0 = off[dst], s1 = off[dst + 1];
    unsigned int qr = *(const unsigned int*)(Q + (size_t)dst * 128 + lane * 2);
    float q0 = bf2f_lo(qr), q1 = bf2f_hi(qr);
    float m = -INFINITY, den = 0.f, a0 = 0.f, a1 = 0.f;
    for (int j = s0; j < s1; ++j) {
        int src = csrc[j];
        const unsigned short* kvrow = KV + (size_t)src * 256;
        unsigned int kr = *(const unsigned int*)(kvrow + lane * 2);
        unsigned int vr = *(const unsigned int*)(kvrow + 128 + lane * 2);
        float t = q0 * bf2f_lo(kr) + q1 * bf2f_hi(kr);
        t += __shfl_xor(t, 1);
        t += __shfl_xor(t, 2);
        t += __shfl_xor(t, 4);
        t += __shfl_xor(t, 8);           // alpha for this head, uniform in 16-lane group
        float nm = fmaxf(m, t);
        float sc = __expf(m - nm);
        float p  = __expf(t - nm);
        den = den * sc + p;
        a0 = a0 * sc + p * bf2f_lo(vr);
        a1 = a1 * sc + p * bf2f_hi(vr);
        m = nm;
    }
    float inv = (s1 > s0) ? 1.f / den : 0.f;
    float r0 = a0 * inv, r1 = a1 * inv;
    if (GELU_OUT) { r0 = geluf(r0); r1 = geluf(r1); }
    unsigned int o = (unsigned int)f2bf(r0) | ((unsigned int)f2bf(r1) << 16);
    *(unsigned int*)(out + (size_t)dst * 128 + lane * 2) = o;
}

// ---------------------------------------------------------------- output head: logits -> softmax -> segment sums
__global__ void k_head(const unsigned short* __restrict__ h2, const float* __restrict__ w2,
                       const float* __restrict__ b2, const int* __restrict__ batch,
                       int N, float* __restrict__ gsum, float* __restrict__ gcnt) {
    int node = blockIdx.x * 256 + threadIdx.x;
    if (node >= N) return;
    const uint4* hp = (const uint4*)(h2 + (size_t)node * 128);
    float l0 = b2[0], l1 = b2[1];
    #pragma unroll
    for (int j = 0; j < 16; ++j) {
        uint4 raw = hp[j];
        float e[8];
        e[0] = bf2f_lo(raw.x); e[1] = bf2f_hi(raw.x);
        e[2] = bf2f_lo(raw.y); e[3] = bf2f_hi(raw.y);
        e[4] = bf2f_lo(raw.z); e[5] = bf2f_hi(raw.z);
        e[6] = bf2f_lo(raw.w); e[7] = bf2f_hi(raw.w);
        int k = j * 8;
        #pragma unroll
        for (int q = 0; q < 8; ++q) {
            l0 += e[q] * w2[(k + q) * 2];
            l1 += e[q] * w2[(k + q) * 2 + 1];
        }
    }
    float m = fmaxf(l0, l1);
    float e0 = __expf(l0 - m), e1 = __expf(l1 - m);
    float inv = 1.f / (e0 + e1);
    int b = batch[node];
    atomicAdd(&gsum[b * 2 + 0], e0 * inv);
    atomicAdd(&gsum[b * 2 + 1], e1 * inv);
    atomicAdd(&gcnt[b], 1.f);
}
__global__ void k_finalize(const float* __restrict__ gsum, const float* __restrict__ gcnt,
                           float* __restrict__ out, int n) {
    int i = blockIdx.x * 256 + threadIdx.x;
    if (i < n) out[i] = gsum[i] / fmaxf(gcnt[i >> 1], 1.f);
}

// ---------------------------------------------------------------- host
extern "C" void kernel_launch(void* const* d_in, const int* in_sizes, int n_in,
                              void* d_out, int out_size, void* d_ws, size_t ws_size,
                              hipStream_t stream) {
    const float* x_var    = (const float*)d_in[0];
    const float* x_con    = (const float*)d_in[1];
    const float* mlp_in_w = (const float*)d_in[2];
    const float* mlp_in_b = (const float*)d_in[3];
    const float* mow0 = (const float*)d_in[4];
    const float* mob0 = (const float*)d_in[5];
    const float* mow1 = (const float*)d_in[6];
    const float* mob1 = (const float*)d_in[7];
    const float* mow2 = (const float*)d_in[8];
    const float* mob2 = (const float*)d_in[9];
    const float* k_w  = (const float*)d_in[10];
    const float* k_b  = (const float*)d_in[11];
    const float* q_w  = (const float*)d_in[12];
    const float* q_b  = (const float*)d_in[13];
    const float* v_w  = (const float*)d_in[14];
    const float* v_b  = (const float*)d_in[15];
    const float* a_w  = (const float*)d_in[16];
    const float* a_b  = (const float*)d_in[17];
    const float* skipP = (const float*)d_in[18];
    const float* a_rel = (const float*)d_in[19];
    const float* m_rel = (const float*)d_in[20];
    const float* p_rel = (const float*)d_in[21];
    const int* edge_vc = (const int*)d_in[22];
    const int* edge_cv = (const int*)d_in[23];
    const int* batch   = (const int*)d_in[24];

    const int Nv = in_sizes[0] / 128;
    const int Nc = in_sizes[1] / 128;
    const int E  = in_sizes[22] / 2;
    const int G  = out_size / 2;
    const int nmax = Nv > Nc ? Nv : Nc;

    // ---- workspace layout
    float* fbase = (float*)d_ws;
    size_t fo = 0;
    auto falloc = [&](size_t n) { float* p = fbase + fo; fo += n; return p; };
    float* Wkv  = falloc((size_t)4 * 128 * 256);
    float* Bkv  = falloc(4 * 256);
    float* gsum = falloc((size_t)G * 2);
    float* gcnt = falloc((size_t)G * 2);   // padded to keep 16B alignment downstream

    unsigned short* bbase = (unsigned short*)(fbase + fo);
    size_t bo = 0;
    auto balloc = [&](size_t n) { unsigned short* p = bbase + bo; bo += n; return p; };
    unsigned short* Wswz  = balloc((size_t)24 * 16384);
    unsigned short* cur0  = balloc((size_t)Nv * 128);
    unsigned short* cur1  = balloc((size_t)Nc * 128);
    unsigned short* Qbuf  = balloc((size_t)nmax * 128);
    unsigned short* KVbuf = balloc((size_t)nmax * 256);
    unsigned short* agg0  = balloc((size_t)Nv * 128);
    unsigned short* agg1  = balloc((size_t)Nc * 128);

    int* ibase = (int*)(bbase + bo);
    size_t io = 0;
    auto ialloc = [&](size_t n) { int* p = ibase + io; io += n; return p; };
    int* offVC = ialloc((size_t)Nc + 1);
    int* srcVC = ialloc(E);
    int* offCV = ialloc((size_t)Nv + 1);
    int* srcCV = ialloc(E);
    int* deg      = ialloc(nmax);
    int* cursor   = ialloc(nmax);
    int* partials = ialloc(256);

    size_t need = (char*)(ibase + io) - (char*)d_ws;
    if (need > ws_size) return;

    const int eb = (E + 255) / 256;

    // ---- cast inputs to bf16 (into agg0/agg1, free at this point)
    k_cast<<<(Nv * 32 + 255) / 256, 256, 0, stream>>>(x_var, agg0, Nv * 32);
    k_cast<<<(Nc * 32 + 255) / 256, 256, 0, stream>>>(x_con, agg1, Nc * 32);

    // ---- CSR builds
    auto buildCSR = [&](const int* edges, int n_dst, int* offA, int* csrcA) {
        int nzb = (n_dst + 255) / 256;
        k_zero<<<nzb, 256, 0, stream>>>(deg, n_dst);
        k_hist<<<eb, 256, 0, stream>>>(edges + E, E, deg);
        k_scan_block<<<nzb, 256, 0, stream>>>(deg, n_dst, offA, partials);
        k_scan_partials<<<1, 256, 0, stream>>>(partials, nzb);
        k_scan_add<<<nzb, 256, 0, stream>>>(offA, partials, n_dst);
        k_zero<<<nzb, 256, 0, stream>>>(cursor, n_dst);
        k_scatter<<<eb, 256, 0, stream>>>(edges, E, offA, cursor, csrcA);
    };
    buildCSR(edge_vc, Nc, offVC, srcVC);
    buildCSR(edge_cv, Nv, offCV, srcCV);

    // ---- fold rel transforms (fp32), then swizzle ALL weights to bf16 B-fragment order
    k_prep<<<dim3((129 * 256 + 255) / 256, 4), 256, 0, stream>>>(
        k_w, k_b, v_w, v_b, a_rel, m_rel, p_rel, Wkv, Bkv);
    k_swz<<<dim3(64, 24), 256, 0, stream>>>(mlp_in_w, q_w, a_w, mow0, mow1, Wkv, Wswz);

    // ---- MFMA GEMM wrappers
    auto m_plain = [&](const unsigned short* A, int widx, const float* b, unsigned short* C,
                       int N, int ldC, int gy) {
        k_mfma<false, false><<<dim3((N + 63) / 64, gy), 256, 0, stream>>>(
            A, Wswz + (size_t)widx * 16384, b, C, N, ldC, nullptr, nullptr);
    };
    auto m_relu = [&](const unsigned short* A, int widx, const float* b, unsigned short* C, int N) {
        k_mfma<true, false><<<dim3((N + 63) / 64, 1), 256, 0, stream>>>(
            A, Wswz + (size_t)widx * 16384, b, C, N, 128, nullptr, nullptr);
    };
    auto m_skip = [&](const unsigned short* A, int widx, const float* b, unsigned short* C,
                      int N, const unsigned short* xold, const float* sp) {
        k_mfma<false, true><<<dim3((N + 63) / 64, 1), 256, 0, stream>>>(
            A, Wswz + (size_t)widx * 16384, b, C, N, 128, xold, sp);
    };

    // ---- input MLPs (weights idx 0..2 var, 3..5 con)
    m_relu (agg0, 0, mlp_in_b + 0,   Qbuf,  Nv);
    m_relu (Qbuf, 1, mlp_in_b + 128, KVbuf, Nv);
    m_plain(KVbuf, 2, mlp_in_b + 256, cur0, Nv, 128, 1);
    m_relu (agg1, 3, mlp_in_b + 384, Qbuf,  Nc);
    m_relu (Qbuf, 4, mlp_in_b + 512, KVbuf, Nc);
    m_plain(KVbuf, 5, mlp_in_b + 640, cur1, Nc, 128, 1);

    // ---- HGT layers
    for (int l = 0; l < 2; ++l) {
        int lt0 = l * 2 + 0, lt1 = l * 2 + 1;
        // pass 0: var -> con (q of con; folded k'/v' of var)
        m_plain(cur1, 6 + lt1, q_b + lt1 * 128, Qbuf, Nc, 128, 1);
        m_plain(cur0, 16 + lt0 * 2, Bkv + lt0 * 256, KVbuf, Nv, 256, 2);
        k_agg<true><<<(Nc + 3) / 4, 256, 0, stream>>>(Qbuf, KVbuf, offVC, srcVC, agg1, Nc);
        // pass 1: con -> var (q of var; folded k'/v' of con)
        m_plain(cur0, 6 + lt0, q_b + lt0 * 128, Qbuf, Nv, 128, 1);
        m_plain(cur1, 16 + lt1 * 2, Bkv + lt1 * 256, KVbuf, Nc, 256, 2);
        k_agg<true><<<(Nv + 3) / 4, 256, 0, stream>>>(Qbuf, KVbuf, offCV, srcCV, agg0, Nv);
        // gated update (gelu already applied in k_agg), in place
        m_skip(agg0, 10 + lt0, a_b + lt0 * 128, cur0, Nv, cur0, skipP + lt0);
        m_skip(agg1, 10 + lt1, a_b + lt1 * 128, cur1, Nc, cur1, skipP + lt1);
    }

    // ---- output head
    m_relu(cur0, 14, mob0, Qbuf, Nv);
    m_relu(Qbuf, 15, mob1, KVbuf, Nv);   // stored with row stride 128
    k_zero<<<(G * 3 + 255) / 256, 256, 0, stream>>>((int*)gsum, G * 3);
    k_head<<<(Nv + 255) / 256, 256, 0, stream>>>(KVbuf, mow2, mob2, batch, Nv, gsum, gcnt);
    k_finalize<<<(G * 2 + 255) / 256, 256, 0, stream>>>(gsum, gcnt, (float*)d_out, G * 2);
}

// Round 4
// 682.452 us; speedup vs baseline: 1.7916x; 1.2670x over previous
//
#include <hip/hip_runtime.h>
#include <cstddef>
#include <cstdint>

typedef __attribute__((ext_vector_type(8))) short short8;
typedef __attribute__((ext_vector_type(4))) float float4v;

// ---------------------------------------------------------------- bf16 helpers
__device__ __forceinline__ float bf2f(unsigned int u16) {
    union { unsigned int i; float f; } v; v.i = u16 << 16; return v.f;
}
__device__ __forceinline__ float bf2f_lo(unsigned int u) {
    union { unsigned int i; float f; } v; v.i = u << 16; return v.f;
}
__device__ __forceinline__ float bf2f_hi(unsigned int u) {
    union { unsigned int i; float f; } v; v.i = u & 0xFFFF0000u; return v.f;
}
__device__ __forceinline__ unsigned short f2bf(float f) {
    union { float f; unsigned int i; } v; v.f = f;
    unsigned int x = v.i;
    unsigned int r = (x + 0x7FFFu + ((x >> 16) & 1u)) >> 16;
    return (unsigned short)r;
}
__device__ __forceinline__ float geluf(float x) {
    return 0.5f * x * (1.0f + erff(x * 0.70710678118654752f));
}

// ---------------------------------------------------------------- zero fill
__global__ void k_zero(int* __restrict__ p, int n) {
    int i = blockIdx.x * 256 + threadIdx.x;
    if (i < n) p[i] = 0;
}

// ---------------------------------------------------------------- cast both inputs fp32 -> bf16 into stacked buffer
__global__ void k_cast2(const float* __restrict__ xa, const float* __restrict__ xb,
                        unsigned short* __restrict__ o, int n4a, int n4tot) {
    int i = blockIdx.x * 256 + threadIdx.x;
    if (i >= n4tot) return;
    const float* src = (i < n4a) ? (xa + (size_t)i * 4) : (xb + (size_t)(i - n4a) * 4);
    float4 v = *(const float4*)src;
    ushort4 u;
    u.x = f2bf(v.x); u.y = f2bf(v.y); u.z = f2bf(v.z); u.w = f2bf(v.w);
    *(ushort4*)(o + (size_t)i * 4) = u;
}

// ---------------------------------------------------------------- prep: fold a_rel (+p_rel/sqrt D) / m_rel into K/V weights (fp32)
__global__ void k_prep(const float* __restrict__ kw, const float* __restrict__ kb,
                       const float* __restrict__ vw, const float* __restrict__ vb,
                       const float* __restrict__ arel, const float* __restrict__ mrel,
                       const float* __restrict__ prel,
                       float* __restrict__ Wkv, float* __restrict__ Bkv) {
    int lt = blockIdx.y;
    int tid = blockIdx.x * 256 + threadIdx.x;
    if (tid >= 129 * 256) return;
    int k = tid >> 8;
    int c = tid & 255;
    int sec = c >> 7, cc = c & 127, h = cc >> 5, e = cc & 31;
    const float* Wsrc = sec ? vw : kw;
    const float* Bsrc = sec ? vb : kb;
    const float* R    = sec ? mrel : arel;
    float scale = sec ? 1.0f : prel[lt * 4 + h] * 0.17677669529663687f;
    const float* rp = R + (size_t)(lt * 4 + h) * 1024 + e;
    const float* wp = (k < 128) ? (Wsrc + (size_t)lt * 16384 + (size_t)k * 128 + h * 32)
                                : (Bsrc + lt * 128 + h * 32);
    float s = 0.f;
    #pragma unroll 8
    for (int d = 0; d < 32; ++d) s += wp[d] * rp[(size_t)d * 32];
    s *= scale;
    if (k < 128) Wkv[(size_t)lt * 128 * 256 + (size_t)k * 256 + c] = s;
    else         Bkv[lt * 256 + c] = s;
}

// ---------------------------------------------------------------- swizzle weights into MFMA B-fragment order (bf16), 24 units
__global__ void k_swz(const float* __restrict__ mlp_in_w, const float* __restrict__ q_w,
                      const float* __restrict__ a_w, const float* __restrict__ mow0,
                      const float* __restrict__ mow1, const float* __restrict__ Wkv,
                      unsigned short* __restrict__ Wswz) {
    int idx = blockIdx.y;
    int f = blockIdx.x * 256 + threadIdx.x;
    if (f >= 16384) return;
    int j = f & 7, l = (f >> 3) & 63, t = (f >> 9) & 7, s = f >> 12;
    int k = s * 32 + (l >> 4) * 8 + j;
    int n = t * 16 + (l & 15);
    const float* src; int ld = 128;
    if (idx < 6)        src = mlp_in_w + (size_t)idx * 16384;
    else if (idx < 10)  src = q_w + (size_t)(idx - 6) * 16384;
    else if (idx < 14)  src = a_w + (size_t)(idx - 10) * 16384;
    else if (idx == 14) src = mow0;
    else if (idx == 15) src = mow1;
    else { int u = idx - 16; src = Wkv + (size_t)(u >> 1) * 32768 + (u & 1) * 128; ld = 256; }
    Wswz[(size_t)idx * 16384 + f] = f2bf(src[(size_t)k * ld + n]);
}

// ---------------------------------------------------------------- 16-row x 128-col MFMA tile accumulate
__device__ __forceinline__ void tile16(const unsigned short* __restrict__ A, int N, int mbase,
                                       int quad, int mrow, const unsigned short* __restrict__ Bu,
                                       float4v acc[8]) {
    int r0 = mbase + mrow; if (r0 >= N) r0 = N - 1;
    const unsigned short* ap = A + (size_t)r0 * 128 + quad * 8;
    #pragma unroll
    for (int s = 0; s < 4; ++s) {
        short8 av = *(const short8*)(ap + s * 32);
        #pragma unroll
        for (int t = 0; t < 8; ++t) {
            short8 bv = *(const short8*)(Bu + (s * 8 + t) * 512);
            acc[t] = __builtin_amdgcn_mfma_f32_16x16x32_bf16(av, bv, acc[t], 0, 0, 0);
        }
    }
}

// ---------------------------------------------------------------- row-split stacked GEMM (MLPs, gated update, head)
// rows < Nsplit use unitA/biasA/sA, rows >= Nsplit use unitB/... ; C ld = 128.
template<bool RELU, bool SKIP>
__global__ __launch_bounds__(256) void k_gemmrs(
    const unsigned short* __restrict__ A, const unsigned short* __restrict__ Wswz,
    int unitA, int unitB, const float* __restrict__ biasA, const float* __restrict__ biasB,
    unsigned short* __restrict__ C, int N, int Nsplit,
    const unsigned short* __restrict__ Xold,
    const float* __restrict__ spA, const float* __restrict__ spB) {
    const int lane = threadIdx.x & 63, wave = threadIdx.x >> 6;
    const int quad = lane >> 4, mrow = lane & 15;
    const int mbase = blockIdx.x * 64 + wave * 16;
    if (mbase >= N) return;
    const bool first = mbase < Nsplit;
    const unsigned short* Bu = Wswz + (size_t)(first ? unitA : unitB) * 16384 + lane * 8;
    const float* bias = first ? biasA : biasB;
    float4v acc[8];
    #pragma unroll
    for (int t = 0; t < 8; ++t) acc[t] = (float4v){0.f, 0.f, 0.f, 0.f};
    tile16(A, N, mbase, quad, mrow, Bu, acc);
    float g = 0.f, og = 0.f;
    if (SKIP) {
        const float* sp = first ? spA : spB;
        g = 1.f / (1.f + __expf(-sp[0])); og = 1.f - g;
    }
    #pragma unroll
    for (int t = 0; t < 8; ++t) {
        int col = t * 16 + mrow;
        float b = bias[col];
        #pragma unroll
        for (int r = 0; r < 4; ++r) {
            int row = mbase + quad * 4 + r;
            if (row < N) {
                float v = acc[t][r] + b;
                if (RELU) v = fmaxf(v, 0.f);
                if (SKIP) v = g * v + og * bf2f(Xold[(size_t)row * 128 + col]);
                C[(size_t)row * 128 + col] = f2bf(v);
            }
        }
    }
}

// ---------------------------------------------------------------- fused Q + KV GEMM for one attention pass
// y=0: Q = Ad @ unitQ -> Qb (ld 128);  y=1,2: KV col-block = As @ unit(K0+y-1) -> KVb (ld 256)
__global__ __launch_bounds__(256) void k_gemmqkv(
    const unsigned short* __restrict__ Ad, const unsigned short* __restrict__ As,
    const unsigned short* __restrict__ Wswz, int unitQ, int unitK0,
    const float* __restrict__ qb, const float* __restrict__ kvb,
    unsigned short* __restrict__ Qb, unsigned short* __restrict__ KVb,
    int Nd, int Ns) {
    const int lane = threadIdx.x & 63, wave = threadIdx.x >> 6;
    const int quad = lane >> 4, mrow = lane & 15;
    const int mbase = blockIdx.x * 64 + wave * 16;
    const int y = blockIdx.y;
    const unsigned short* A; unsigned short* C; const float* bias;
    int N, ldC, cbase, unit;
    if (y == 0) { A = Ad; C = Qb; N = Nd; ldC = 128; cbase = 0; unit = unitQ; bias = qb; }
    else { A = As; C = KVb; N = Ns; ldC = 256; cbase = (y - 1) * 128; unit = unitK0 + (y - 1); bias = kvb + (y - 1) * 128; }
    if (mbase >= N) return;
    const unsigned short* Bu = Wswz + (size_t)unit * 16384 + lane * 8;
    float4v acc[8];
    #pragma unroll
    for (int t = 0; t < 8; ++t) acc[t] = (float4v){0.f, 0.f, 0.f, 0.f};
    tile16(A, N, mbase, quad, mrow, Bu, acc);
    #pragma unroll
    for (int t = 0; t < 8; ++t) {
        int col = t * 16 + mrow;
        float b = bias[col];
        #pragma unroll
        for (int r = 0; r < 4; ++r) {
            int row = mbase + quad * 4 + r;
            if (row < N) C[(size_t)row * ldC + cbase + col] = f2bf(acc[t][r] + b);
        }
    }
}

// ---------------------------------------------------------------- CSR build (both edge types in one dispatch via blockIdx.y)
__global__ void k_hist2(const int* __restrict__ evc, const int* __restrict__ ecv, int E,
                        int* __restrict__ deg2, int Nc) {
    int e = blockIdx.x * 256 + threadIdx.x;
    if (e >= E) return;
    if (blockIdx.y == 0) atomicAdd(&deg2[evc[E + e]], 1);
    else                 atomicAdd(&deg2[Nc + ecv[E + e]], 1);
}
__global__ void k_scan_block2(const int* __restrict__ deg2, int Nc, int Nv,
                              int* __restrict__ offVC, int* __restrict__ offCV,
                              int* __restrict__ partials) {
    __shared__ int s[256];
    int y = blockIdx.y;
    int n = y ? Nv : Nc;
    const int* deg = deg2 + (y ? Nc : 0);
    int* off = y ? offCV : offVC;
    int i = blockIdx.x * 256 + threadIdx.x;
    s[threadIdx.x] = (i < n) ? deg[i] : 0;
    __syncthreads();
    for (int d = 1; d < 256; d <<= 1) {
        int t = (threadIdx.x >= d) ? s[threadIdx.x - d] : 0;
        __syncthreads();
        s[threadIdx.x] += t;
        __syncthreads();
    }
    if (i < n) off[i + 1] = s[threadIdx.x];
    if (threadIdx.x == 255) partials[y * 256 + blockIdx.x] = s[255];
}
__global__ void k_scan_partials2(int* __restrict__ partials, int nb) {
    __shared__ int s[256];
    int* p = partials + blockIdx.x * 256;
    s[threadIdx.x] = (threadIdx.x < nb) ? p[threadIdx.x] : 0;
    __syncthreads();
    for (int d = 1; d < 256; d <<= 1) {
        int t = (threadIdx.x >= d) ? s[threadIdx.x - d] : 0;
        __syncthreads();
        s[threadIdx.x] += t;
        __syncthreads();
    }
    if (threadIdx.x < nb) p[threadIdx.x] = s[threadIdx.x];
}
__global__ void k_scan_add2(int* __restrict__ offVC, int* __restrict__ offCV,
                            const int* __restrict__ partials, int Nc, int Nv) {
    int y = blockIdx.y;
    int n = y ? Nv : Nc;
    int* off = y ? offCV : offVC;
    const int* p = partials + y * 256;
    int i = blockIdx.x * 256 + threadIdx.x;
    if (i == 0) off[0] = 0;
    if (i < n) {
        int b = i >> 8;
        if (b > 0) off[i + 1] += p[b - 1];
    }
}
__global__ void k_scatter2(const int* __restrict__ evc, const int* __restrict__ ecv, int E,
                           const int* __restrict__ offVC, const int* __restrict__ offCV,
                           int* __restrict__ cursor2, int Nc,
                           int* __restrict__ srcVC, int* __restrict__ srcCV) {
    int e = blockIdx.x * 256 + threadIdx.x;
    if (e >= E) return;
    if (blockIdx.y == 0) {
        int d = evc[E + e];
        int pos = offVC[d] + atomicAdd(&cursor2[d], 1);
        srcVC[pos] = evc[e];
    } else {
        int d = ecv[E + e];
        int pos = offCV[d] + atomicAdd(&cursor2[Nc + d], 1);
        srcCV[pos] = ecv[e];
    }
}

// ---------------------------------------------------------------- fused attention: dual-chain online softmax + prefetch
// lane owns channels 2*lane, 2*lane+1 (head = lane>>4); butterfly over 16-lane head group.
template<bool GELU_OUT>
__global__ __launch_bounds__(256) void k_agg(
    const unsigned short* __restrict__ Q, const unsigned short* __restrict__ KV,
    const int* __restrict__ off, const int* __restrict__ csrc,
    unsigned short* __restrict__ out, int n_dst) {
    int dst = blockIdx.x * 4 + (threadIdx.x >> 6);
    int lane = threadIdx.x & 63;
    if (dst >= n_dst) return;
    int s0 = off[dst], s1 = off[dst + 1];
    unsigned int qr = *(const unsigned int*)(Q + (size_t)dst * 128 + lane * 2);
    float q0 = bf2f_lo(qr), q1 = bf2f_hi(qr);
    float mA = -INFINITY, dA = 0.f, a0A = 0.f, a1A = 0.f;
    float mB = -INFINITY, dB = 0.f, a0B = 0.f, a1B = 0.f;
    unsigned int krA = 0, vrA = 0, krB = 0, vrB = 0;
    if (s0 < s1) {
        const unsigned short* r = KV + (size_t)csrc[s0] * 256;
        krA = *(const unsigned int*)(r + lane * 2);
        vrA = *(const unsigned int*)(r + 128 + lane * 2);
    }
    if (s0 + 1 < s1) {
        const unsigned short* r = KV + (size_t)csrc[s0 + 1] * 256;
        krB = *(const unsigned int*)(r + lane * 2);
        vrB = *(const unsigned int*)(r + 128 + lane * 2);
    }
    for (int j = s0; j < s1; j += 2) {
        unsigned int ckA = krA, cvA = vrA, ckB = krB, cvB = vrB;
        bool hasB = (j + 1 < s1);
        if (j + 2 < s1) {   // prefetch next pair
            const unsigned short* r = KV + (size_t)csrc[j + 2] * 256;
            krA = *(const unsigned int*)(r + lane * 2);
            vrA = *(const unsigned int*)(r + 128 + lane * 2);
        }
        if (j + 3 < s1) {
            const unsigned short* r = KV + (size_t)csrc[j + 3] * 256;
            krB = *(const unsigned int*)(r + lane * 2);
            vrB = *(const unsigned int*)(r + 128 + lane * 2);
        }
        float tA = q0 * bf2f_lo(ckA) + q1 * bf2f_hi(ckA);
        float tB = q0 * bf2f_lo(ckB) + q1 * bf2f_hi(ckB);
        tA += __shfl_xor(tA, 1);  tB += __shfl_xor(tB, 1);
        tA += __shfl_xor(tA, 2);  tB += __shfl_xor(tB, 2);
        tA += __shfl_xor(tA, 4);  tB += __shfl_xor(tB, 4);
        tA += __shfl_xor(tA, 8);  tB += __shfl_xor(tB, 8);
        {
            float nm = fmaxf(mA, tA);
            float sc = __expf(mA - nm);
            float p  = __expf(tA - nm);
            dA = dA * sc + p;
            a0A = a0A * sc + p * bf2f_lo(cvA);
            a1A = a1A * sc + p * bf2f_hi(cvA);
            mA = nm;
        }
        if (hasB) {
            float nm = fmaxf(mB, tB);
            float sc = __expf(mB - nm);
            float p  = __expf(tB - nm);
            dB = dB * sc + p;
            a0B = a0B * sc + p * bf2f_lo(cvB);
            a1B = a1B * sc + p * bf2f_hi(cvB);
            mB = nm;
        }
    }
    float r0 = 0.f, r1 = 0.f;
    if (s1 > s0) {
        float nm = fmaxf(mA, mB);
        float sA = __expf(mA - nm);                       // mA finite when any edge
        float sB = (mB == -INFINITY) ? 0.f : __expf(mB - nm);
        float den = dA * sA + dB * sB;
        float inv = 1.f / den;
        r0 = (a0A * sA + a0B * sB) * inv;
        r1 = (a1A * sA + a1B * sB) * inv;
    }
    if (GELU_OUT) { r0 = geluf(r0); r1 = geluf(r1); }
    unsigned int o = (unsigned int)f2bf(r0) | ((unsigned int)f2bf(r1) << 16);
    *(unsigned int*)(out + (size_t)dst * 128 + lane * 2) = o;
}

// ---------------------------------------------------------------- output head with LDS binning (batch sorted)
__global__ __launch_bounds__(256) void k_head(
    const unsigned short* __restrict__ h2, const float* __restrict__ w2,
    const float* __restrict__ b2, const int* __restrict__ batch,
    int N, int G, float* __restrict__ gsum, float* __restrict__ gcnt) {
    __shared__ float sb[64][3];
    int t = threadIdx.x;
    for (int i = t; i < 192; i += 256) ((float*)sb)[i] = 0.f;
    __syncthreads();
    int base = blockIdx.x * 256;
    int bmin = batch[base];
    int node = base + t;
    if (node < N) {
        const uint4* hp = (const uint4*)(h2 + (size_t)node * 128);
        float l0 = b2[0], l1 = b2[1];
        #pragma unroll
        for (int j = 0; j < 16; ++j) {
            uint4 raw = hp[j];
            float e[8];
            e[0] = bf2f_lo(raw.x); e[1] = bf2f_hi(raw.x);
            e[2] = bf2f_lo(raw.y); e[3] = bf2f_hi(raw.y);
            e[4] = bf2f_lo(raw.z); e[5] = bf2f_hi(raw.z);
            e[6] = bf2f_lo(raw.w); e[7] = bf2f_hi(raw.w);
            int k = j * 8;
            #pragma unroll
            for (int q = 0; q < 8; ++q) {
                l0 += e[q] * w2[(k + q) * 2];
                l1 += e[q] * w2[(k + q) * 2 + 1];
            }
        }
        float m = fmaxf(l0, l1);
        float e0 = __expf(l0 - m), e1 = __expf(l1 - m);
        float inv = 1.f / (e0 + e1);
        float p0 = e0 * inv, p1 = e1 * inv;
        int b = batch[node];
        int rel = b - bmin;
        if (rel < 64) {
            atomicAdd(&sb[rel][0], p0);
            atomicAdd(&sb[rel][1], p1);
            atomicAdd(&sb[rel][2], 1.f);
        } else {
            atomicAdd(&gsum[b * 2 + 0], p0);
            atomicAdd(&gsum[b * 2 + 1], p1);
            atomicAdd(&gcnt[b], 1.f);
        }
    }
    __syncthreads();
    for (int i = t; i < 64; i += 256) {
        float c = sb[i][2];
        if (c != 0.f && bmin + i < G) {
            atomicAdd(&gsum[(bmin + i) * 2 + 0], sb[i][0]);
            atomicAdd(&gsum[(bmin + i) * 2 + 1], sb[i][1]);
            atomicAdd(&gcnt[bmin + i], c);
        }
    }
}
__global__ void k_finalize(const float* __restrict__ gsum, const float* __restrict__ gcnt,
                           float* __restrict__ out, int n) {
    int i = blockIdx.x * 256 + threadIdx.x;
    if (i < n) out[i] = gsum[i] / fmaxf(gcnt[i >> 1], 1.f);
}

// ---------------------------------------------------------------- host
extern "C" void kernel_launch(void* const* d_in, const int* in_sizes, int n_in,
                              void* d_out, int out_size, void* d_ws, size_t ws_size,
                              hipStream_t stream) {
    const float* x_var    = (const float*)d_in[0];
    const float* x_con    = (const float*)d_in[1];
    const float* mlp_in_w = (const float*)d_in[2];
    const float* mlp_in_b = (const float*)d_in[3];
    const float* mow0 = (const float*)d_in[4];
    const float* mob0 = (const float*)d_in[5];
    const float* mow1 = (const float*)d_in[6];
    const float* mob1 = (const float*)d_in[7];
    const float* mow2 = (const float*)d_in[8];
    const float* mob2 = (const float*)d_in[9];
    const float* k_w  = (const float*)d_in[10];
    const float* k_b  = (const float*)d_in[11];
    const float* q_w  = (const float*)d_in[12];
    const float* q_b  = (const float*)d_in[13];
    const float* v_w  = (const float*)d_in[14];
    const float* v_b  = (const float*)d_in[15];
    const float* a_w  = (const float*)d_in[16];
    const float* a_b  = (const float*)d_in[17];
    const float* skipP = (const float*)d_in[18];
    const float* a_rel = (const float*)d_in[19];
    const float* m_rel = (const float*)d_in[20];
    const float* p_rel = (const float*)d_in[21];
    const int* edge_vc = (const int*)d_in[22];
    const int* edge_cv = (const int*)d_in[23];
    const int* batch   = (const int*)d_in[24];

    const int Nv = in_sizes[0] / 128;
    const int Nc = in_sizes[1] / 128;
    const int E  = in_sizes[22] / 2;
    const int G  = out_size / 2;
    const int nmax = Nv > Nc ? Nv : Nc;
    const int NT = Nv + Nc;

    // ---- workspace layout
    float* fbase = (float*)d_ws;
    size_t fo = 0;
    auto falloc = [&](size_t n) { float* p = fbase + fo; fo += n; return p; };
    float* Wkv  = falloc((size_t)4 * 128 * 256);
    float* Bkv  = falloc(4 * 256);
    float* gsum = falloc((size_t)G * 2);
    float* gcnt = falloc((size_t)G * 2);

    unsigned short* bbase = (unsigned short*)(fbase + fo);
    size_t bo = 0;
    auto balloc = [&](size_t n) { unsigned short* p = bbase + bo; bo += n; return p; };
    unsigned short* Wswz = balloc((size_t)24 * 16384);
    unsigned short* curS = balloc((size_t)NT * 128);   // cur0 | cur1 stacked
    unsigned short* aggS = balloc((size_t)NT * 128);   // also xin / MLP ping buffer
    unsigned short* tmpS = balloc((size_t)nmax * 384); // Qbuf | KVbuf (also MLP pong)
    unsigned short* cur0 = curS, *cur1 = curS + (size_t)Nv * 128;
    unsigned short* agg0 = aggS, *agg1 = aggS + (size_t)Nv * 128;
    unsigned short* Qbuf = tmpS;
    unsigned short* KVbuf = tmpS + (size_t)nmax * 128;

    int* ibase = (int*)(bbase + bo);
    size_t io = 0;
    auto ialloc = [&](size_t n) { int* p = ibase + io; io += n; return p; };
    int* offVC = ialloc((size_t)Nc + 1);
    int* offCV = ialloc((size_t)Nv + 1);
    int* srcVC = ialloc(E);
    int* srcCV = ialloc(E);
    int* deg2  = ialloc((size_t)NT);     // degrees, then reused as cursors
    int* partials = ialloc(512);

    size_t need = (char*)(ibase + io) - (char*)d_ws;
    if (need > ws_size) return;

    const int eb = (E + 255) / 256;
    const int nzb = (nmax + 255) / 256;

    // ---- cast inputs to stacked bf16 (into aggS)
    k_cast2<<<(NT * 32 + 255) / 256, 256, 0, stream>>>(x_var, x_con, aggS, Nv * 32, NT * 32);

    // ---- CSR build (both types per dispatch)
    k_zero<<<(NT + 255) / 256, 256, 0, stream>>>(deg2, NT);
    k_hist2<<<dim3(eb, 2), 256, 0, stream>>>(edge_vc, edge_cv, E, deg2, Nc);
    k_scan_block2<<<dim3(nzb, 2), 256, 0, stream>>>(deg2, Nc, Nv, offVC, offCV, partials);
    k_scan_partials2<<<2, 256, 0, stream>>>(partials, nzb);
    k_scan_add2<<<dim3(nzb, 2), 256, 0, stream>>>(offVC, offCV, partials, Nc, Nv);
    k_zero<<<(NT + 255) / 256, 256, 0, stream>>>(deg2, NT);      // reuse as cursors
    k_scatter2<<<dim3(eb, 2), 256, 0, stream>>>(edge_vc, edge_cv, E, offVC, offCV, deg2, Nc, srcVC, srcCV);

    // ---- weight prep + swizzle
    k_prep<<<dim3((129 * 256 + 255) / 256, 4), 256, 0, stream>>>(
        k_w, k_b, v_w, v_b, a_rel, m_rel, p_rel, Wkv, Bkv);
    k_swz<<<dim3(64, 24), 256, 0, stream>>>(mlp_in_w, q_w, a_w, mow0, mow1, Wkv, Wswz);

    const int gNT = (NT + 63) / 64;
    const int gNv = (Nv + 63) / 64;

    // ---- input MLPs, stacked var|con (units 0..2 / 3..5); ping-pong aggS <-> tmpS
    k_gemmrs<true, false><<<gNT, 256, 0, stream>>>(
        aggS, Wswz, 0, 3, mlp_in_b + 0, mlp_in_b + 384, tmpS, NT, Nv, nullptr, nullptr, nullptr);
    k_gemmrs<true, false><<<gNT, 256, 0, stream>>>(
        tmpS, Wswz, 1, 4, mlp_in_b + 128, mlp_in_b + 512, aggS, NT, Nv, nullptr, nullptr, nullptr);
    k_gemmrs<false, false><<<gNT, 256, 0, stream>>>(
        aggS, Wswz, 2, 5, mlp_in_b + 256, mlp_in_b + 640, curS, NT, Nv, nullptr, nullptr, nullptr);

    // ---- HGT layers
    for (int l = 0; l < 2; ++l) {
        int lt0 = l * 2 + 0, lt1 = l * 2 + 1;
        // pass 0: var -> con (Q of con, folded K'/V' of var)
        k_gemmqkv<<<dim3((nmax + 63) / 64, 3), 256, 0, stream>>>(
            cur1, cur0, Wswz, 6 + lt1, 16 + lt0 * 2, q_b + lt1 * 128, Bkv + lt0 * 256,
            Qbuf, KVbuf, Nc, Nv);
        k_agg<true><<<(Nc + 3) / 4, 256, 0, stream>>>(Qbuf, KVbuf, offVC, srcVC, agg1, Nc);
        // pass 1: con -> var
        k_gemmqkv<<<dim3((nmax + 63) / 64, 3), 256, 0, stream>>>(
            cur0, cur1, Wswz, 6 + lt0, 16 + lt1 * 2, q_b + lt0 * 128, Bkv + lt1 * 256,
            Qbuf, KVbuf, Nv, Nc);
        k_agg<true><<<(Nv + 3) / 4, 256, 0, stream>>>(Qbuf, KVbuf, offCV, srcCV, agg0, Nv);
        // gated update, stacked, in place (gelu applied in k_agg)
        k_gemmrs<false, true><<<gNT, 256, 0, stream>>>(
            aggS, Wswz, 10 + lt0, 10 + lt1, a_b + lt0 * 128, a_b + lt1 * 128,
            curS, NT, Nv, curS, skipP + lt0, skipP + lt1);
    }

    // ---- output head (var nodes only)
    k_gemmrs<true, false><<<gNv, 256, 0, stream>>>(
        cur0, Wswz, 14, 14, mob0, mob0, Qbuf, Nv, Nv, nullptr, nullptr, nullptr);
    k_gemmrs<true, false><<<gNv, 256, 0, stream>>>(
        Qbuf, Wswz, 15, 15, mob1, mob1, KVbuf, Nv, Nv, nullptr, nullptr, nullptr);
    k_zero<<<(G * 3 + 255) / 256, 256, 0, stream>>>((int*)gsum, G * 3);
    k_head<<<(Nv + 255) / 256, 256, 0, stream>>>(KVbuf, mow2, mob2, batch, Nv, G, gsum, gcnt);
    k_finalize<<<(G * 2 + 255) / 256, 256, 0, stream>>>(gsum, gcnt, (float*)d_out, G * 2);
}

// Round 5
// 658.597 us; speedup vs baseline: 1.8565x; 1.0362x over previous
//
#include <hip/hip_runtime.h>
#include <cstddef>
#include <cstdint>

typedef __attribute__((ext_vector_type(8))) short short8;
typedef __attribute__((ext_vector_type(4))) float float4v;

// ---------------------------------------------------------------- bf16 helpers
__device__ __forceinline__ float bf2f(unsigned int u16) {
    union { unsigned int i; float f; } v; v.i = u16 << 16; return v.f;
}
__device__ __forceinline__ float bf2f_lo(unsigned int u) {
    union { unsigned int i; float f; } v; v.i = u << 16; return v.f;
}
__device__ __forceinline__ float bf2f_hi(unsigned int u) {
    union { unsigned int i; float f; } v; v.i = u & 0xFFFF0000u; return v.f;
}
__device__ __forceinline__ unsigned short f2bf(float f) {
    union { float f; unsigned int i; } v; v.f = f;
    unsigned int x = v.i;
    unsigned int r = (x + 0x7FFFu + ((x >> 16) & 1u)) >> 16;
    return (unsigned short)r;
}
__device__ __forceinline__ float geluf(float x) {
    return 0.5f * x * (1.0f + erff(x * 0.70710678118654752f));
}

// ---------------------------------------------------------------- zero fill
__global__ void k_zero(int* __restrict__ p, int n) {
    int i = blockIdx.x * 256 + threadIdx.x;
    if (i < n) p[i] = 0;
}

// ---------------------------------------------------------------- prep: fold a_rel (+p_rel/sqrt D) / m_rel into K/V weights (fp32)
__global__ void k_prep(const float* __restrict__ kw, const float* __restrict__ kb,
                       const float* __restrict__ vw, const float* __restrict__ vb,
                       const float* __restrict__ arel, const float* __restrict__ mrel,
                       const float* __restrict__ prel,
                       float* __restrict__ Wkv, float* __restrict__ Bkv) {
    int lt = blockIdx.y;
    int tid = blockIdx.x * 256 + threadIdx.x;
    if (tid >= 129 * 256) return;
    int k = tid >> 8;
    int c = tid & 255;
    int sec = c >> 7, cc = c & 127, h = cc >> 5, e = cc & 31;
    const float* Wsrc = sec ? vw : kw;
    const float* Bsrc = sec ? vb : kb;
    const float* R    = sec ? mrel : arel;
    float scale = sec ? 1.0f : prel[lt * 4 + h] * 0.17677669529663687f;
    const float* rp = R + (size_t)(lt * 4 + h) * 1024 + e;
    const float* wp = (k < 128) ? (Wsrc + (size_t)lt * 16384 + (size_t)k * 128 + h * 32)
                                : (Bsrc + lt * 128 + h * 32);
    float s = 0.f;
    #pragma unroll 8
    for (int d = 0; d < 32; ++d) s += wp[d] * rp[(size_t)d * 32];
    s *= scale;
    if (k < 128) Wkv[(size_t)lt * 128 * 256 + (size_t)k * 256 + c] = s;
    else         Bkv[lt * 256 + c] = s;
}

// ---------------------------------------------------------------- swizzle weights into MFMA B-fragment order (bf16), 24 units
__global__ void k_swz(const float* __restrict__ mlp_in_w, const float* __restrict__ q_w,
                      const float* __restrict__ a_w, const float* __restrict__ mow0,
                      const float* __restrict__ mow1, const float* __restrict__ Wkv,
                      unsigned short* __restrict__ Wswz) {
    int idx = blockIdx.y;
    int f = blockIdx.x * 256 + threadIdx.x;
    if (f >= 16384) return;
    int j = f & 7, l = (f >> 3) & 63, t = (f >> 9) & 7, s = f >> 12;
    int k = s * 32 + (l >> 4) * 8 + j;
    int n = t * 16 + (l & 15);
    const float* src; int ld = 128;
    if (idx < 6)        src = mlp_in_w + (size_t)idx * 16384;
    else if (idx < 10)  src = q_w + (size_t)(idx - 6) * 16384;
    else if (idx < 14)  src = a_w + (size_t)(idx - 10) * 16384;
    else if (idx == 14) src = mow0;
    else if (idx == 15) src = mow1;
    else { int u = idx - 16; src = Wkv + (size_t)(u >> 1) * 32768 + (u & 1) * 128; ld = 256; }
    Wswz[(size_t)idx * 16384 + f] = f2bf(src[(size_t)k * ld + n]);
}

// ---------------------------------------------------------------- MFMA helpers
__device__ __forceinline__ void mfma32(const short8 av[4], const unsigned short* __restrict__ Bu,
                                       float4v acc[8]) {
    #pragma unroll
    for (int s = 0; s < 4; ++s)
        #pragma unroll
        for (int t = 0; t < 8; ++t) {
            short8 bv = *(const short8*)(Bu + (s * 8 + t) * 512);
            acc[t] = __builtin_amdgcn_mfma_f32_16x16x32_bf16(av[s], bv, acc[t], 0, 0, 0);
        }
}

// ---------------------------------------------------------------- row-split stacked GEMM, bf16 A (MLP2/3, a-lin, head)
template<bool RELU, bool SKIP>
__global__ __launch_bounds__(256) void k_gemmrs(
    const unsigned short* __restrict__ A, const unsigned short* __restrict__ Wswz,
    int unitA, int unitB, const float* __restrict__ biasA, const float* __restrict__ biasB,
    unsigned short* __restrict__ C, int N, int Nsplit,
    const unsigned short* __restrict__ Xold,
    const float* __restrict__ spA, const float* __restrict__ spB) {
    const int lane = threadIdx.x & 63, wave = threadIdx.x >> 6;
    const int quad = lane >> 4, mrow = lane & 15;
    const int mbase = blockIdx.x * 64 + wave * 16;
    if (mbase >= N) return;
    const bool first = mbase < Nsplit;
    const unsigned short* Bu = Wswz + (size_t)(first ? unitA : unitB) * 16384 + lane * 8;
    const float* bias = first ? biasA : biasB;
    int r0 = mbase + mrow; if (r0 >= N) r0 = N - 1;
    const unsigned short* ap = A + (size_t)r0 * 128 + quad * 8;
    short8 av[4];
    #pragma unroll
    for (int s = 0; s < 4; ++s) av[s] = *(const short8*)(ap + s * 32);
    float4v acc[8];
    #pragma unroll
    for (int t = 0; t < 8; ++t) acc[t] = (float4v){0.f, 0.f, 0.f, 0.f};
    mfma32(av, Bu, acc);
    float g = 0.f, og = 0.f;
    if (SKIP) {
        const float* sp = first ? spA : spB;
        g = 1.f / (1.f + __expf(-sp[0])); og = 1.f - g;
    }
    #pragma unroll
    for (int t = 0; t < 8; ++t) {
        int col = t * 16 + mrow;
        float b = bias[col];
        #pragma unroll
        for (int r = 0; r < 4; ++r) {
            int row = mbase + quad * 4 + r;
            if (row < N) {
                float v = acc[t][r] + b;
                if (RELU) v = fmaxf(v, 0.f);
                if (SKIP) v = g * v + og * bf2f(Xold[(size_t)row * 128 + col]);
                C[(size_t)row * 128 + col] = f2bf(v);
            }
        }
    }
}

// ---------------------------------------------------------------- MLP layer 1: fp32 A (x_var | x_con stacked), relu
__global__ __launch_bounds__(256) void k_gemmf(
    const float* __restrict__ Xa, const float* __restrict__ Xb,
    const unsigned short* __restrict__ Wswz, int unitA, int unitB,
    const float* __restrict__ biasA, const float* __restrict__ biasB,
    unsigned short* __restrict__ C, int N, int Nsplit) {
    const int lane = threadIdx.x & 63, wave = threadIdx.x >> 6;
    const int quad = lane >> 4, mrow = lane & 15;
    const int mbase = blockIdx.x * 64 + wave * 16;
    if (mbase >= N) return;
    const bool first = mbase < Nsplit;
    const unsigned short* Bu = Wswz + (size_t)(first ? unitA : unitB) * 16384 + lane * 8;
    const float* bias = first ? biasA : biasB;
    int r0 = mbase + mrow; if (r0 >= N) r0 = N - 1;
    const float* ap = (r0 < Nsplit) ? (Xa + (size_t)r0 * 128) : (Xb + (size_t)(r0 - Nsplit) * 128);
    ap += quad * 8;
    short8 av[4];
    #pragma unroll
    for (int s = 0; s < 4; ++s) {
        float4 f0 = *(const float4*)(ap + s * 32);
        float4 f1 = *(const float4*)(ap + s * 32 + 4);
        short8 a;
        a[0] = (short)f2bf(f0.x); a[1] = (short)f2bf(f0.y);
        a[2] = (short)f2bf(f0.z); a[3] = (short)f2bf(f0.w);
        a[4] = (short)f2bf(f1.x); a[5] = (short)f2bf(f1.y);
        a[6] = (short)f2bf(f1.z); a[7] = (short)f2bf(f1.w);
        av[s] = a;
    }
    float4v acc[8];
    #pragma unroll
    for (int t = 0; t < 8; ++t) acc[t] = (float4v){0.f, 0.f, 0.f, 0.f};
    mfma32(av, Bu, acc);
    #pragma unroll
    for (int t = 0; t < 8; ++t) {
        int col = t * 16 + mrow;
        float b = bias[col];
        #pragma unroll
        for (int r = 0; r < 4; ++r) {
            int row = mbase + quad * 4 + r;
            if (row < N)
                C[(size_t)row * 128 + col] = f2bf(fmaxf(acc[t][r] + b, 0.f));
        }
    }
}

// ---------------------------------------------------------------- fused Q + K' + V' per node, one dispatch per layer
// A-fragments loaded once, 3 output units. Waves are node-type pure (Nv % 16 == 0).
__global__ __launch_bounds__(256) void k_qkv(
    const unsigned short* __restrict__ A, const unsigned short* __restrict__ Wswz,
    const float* __restrict__ q_b, const float* __restrict__ Bkv,
    unsigned short* __restrict__ Qs, unsigned short* __restrict__ KVs,
    int NT, int Nv, int l) {
    const int lane = threadIdx.x & 63, wave = threadIdx.x >> 6;
    const int quad = lane >> 4, mrow = lane & 15;
    const int mbase = blockIdx.x * 64 + wave * 16;
    if (mbase >= NT) return;
    const int lt = 2 * l + (mbase >= Nv ? 1 : 0);
    int r0 = mbase + mrow; if (r0 >= NT) r0 = NT - 1;
    const unsigned short* ap = A + (size_t)r0 * 128 + quad * 8;
    short8 av[4];
    #pragma unroll
    for (int s = 0; s < 4; ++s) av[s] = *(const short8*)(ap + s * 32);
    #pragma unroll
    for (int u = 0; u < 3; ++u) {
        int unit = (u == 0) ? (6 + lt) : (16 + lt * 2 + (u - 1));
        const unsigned short* Bu = Wswz + (size_t)unit * 16384 + lane * 8;
        float4v acc[8];
        #pragma unroll
        for (int t = 0; t < 8; ++t) acc[t] = (float4v){0.f, 0.f, 0.f, 0.f};
        mfma32(av, Bu, acc);
        const float* bias = (u == 0) ? (q_b + lt * 128) : (Bkv + lt * 256 + (u - 1) * 128);
        unsigned short* C = (u == 0) ? Qs : KVs;
        const int ldC = (u == 0) ? 128 : 256;
        const int cb = (u == 0) ? 0 : (u - 1) * 128;
        #pragma unroll
        for (int t = 0; t < 8; ++t) {
            int col = t * 16 + mrow;
            float b = bias[col];
            #pragma unroll
            for (int r = 0; r < 4; ++r) {
                int row = mbase + quad * 4 + r;
                if (row < NT) C[(size_t)row * ldC + cb + col] = f2bf(acc[t][r] + b);
            }
        }
    }
}

// ---------------------------------------------------------------- combined CSR build ([var dsts | con dsts])
__global__ void k_hist2(const int* __restrict__ evc, const int* __restrict__ ecv, int E,
                        int* __restrict__ deg, int Nv) {
    int e = blockIdx.x * 256 + threadIdx.x;
    if (e >= E) return;
    if (blockIdx.y == 0) atomicAdd(&deg[Nv + evc[E + e]], 1);   // dst con
    else                 atomicAdd(&deg[ecv[E + e]], 1);        // dst var
}
__global__ void k_scan_block(const int* __restrict__ deg, int n, int* __restrict__ off,
                             int* __restrict__ partials) {
    __shared__ int s[256];
    int i = blockIdx.x * 256 + threadIdx.x;
    s[threadIdx.x] = (i < n) ? deg[i] : 0;
    __syncthreads();
    for (int d = 1; d < 256; d <<= 1) {
        int t = (threadIdx.x >= d) ? s[threadIdx.x - d] : 0;
        __syncthreads();
        s[threadIdx.x] += t;
        __syncthreads();
    }
    if (i < n) off[i + 1] = s[threadIdx.x];
    if (threadIdx.x == 255) partials[blockIdx.x] = s[255];
}
__global__ void k_scan_partials(int* __restrict__ partials, int nb) {   // 512 threads
    __shared__ int s[512];
    s[threadIdx.x] = (threadIdx.x < nb) ? partials[threadIdx.x] : 0;
    __syncthreads();
    for (int d = 1; d < 512; d <<= 1) {
        int t = (threadIdx.x >= d) ? s[threadIdx.x - d] : 0;
        __syncthreads();
        s[threadIdx.x] += t;
        __syncthreads();
    }
    if (threadIdx.x < nb) partials[threadIdx.x] = s[threadIdx.x];
}
__global__ void k_scan_add(int* __restrict__ off, int* __restrict__ cur,
                           const int* __restrict__ partials, int n) {
    int i = blockIdx.x * 256 + threadIdx.x;
    if (i == 0) { off[0] = 0; cur[0] = 0; }
    if (i < n) {
        int b = i >> 8;
        int v = off[i + 1] + ((b > 0) ? partials[b - 1] : 0);
        off[i + 1] = v;
        cur[i + 1] = v;
    }
}
__global__ void k_scatter2(const int* __restrict__ evc, const int* __restrict__ ecv, int E,
                           int* __restrict__ cur, int Nv, int* __restrict__ srcAll) {
    int e = blockIdx.x * 256 + threadIdx.x;
    if (e >= E) return;
    if (blockIdx.y == 0) {                 // edge_vc: src var -> dst con
        int d = Nv + evc[E + e];
        int pos = atomicAdd(&cur[d], 1);
        srcAll[pos] = evc[e];              // var srcs live at stacked base 0
    } else {                               // edge_cv: src con -> dst var
        int d = ecv[E + e];
        int pos = atomicAdd(&cur[d], 1);
        srcAll[pos] = Nv + ecv[e];         // con srcs live at stacked base Nv
    }
}

// ---------------------------------------------------------------- fused attention, both directions, no-max softmax (clamped)
// lane owns channels 2*lane, 2*lane+1 (head = lane>>4); output aliases Q (safe: row-private).
__global__ __launch_bounds__(256) void k_agg(
    const unsigned short* __restrict__ Q, const unsigned short* __restrict__ KV,
    const int* __restrict__ off, const int* __restrict__ csrc,
    unsigned short* __restrict__ out, int NT) {
    int dst = blockIdx.x * 4 + (threadIdx.x >> 6);
    int lane = threadIdx.x & 63;
    if (dst >= NT) return;
    int s0 = off[dst], s1 = off[dst + 1];
    unsigned int qr = *(const unsigned int*)(Q + (size_t)dst * 128 + lane * 2);
    float q0 = bf2f_lo(qr), q1 = bf2f_hi(qr);
    float dA = 0.f, a0A = 0.f, a1A = 0.f;
    float dB = 0.f, a0B = 0.f, a1B = 0.f;
    unsigned int krA = 0, vrA = 0, krB = 0, vrB = 0;
    if (s0 < s1) {
        const unsigned short* r = KV + (size_t)csrc[s0] * 256;
        krA = *(const unsigned int*)(r + lane * 2);
        vrA = *(const unsigned int*)(r + 128 + lane * 2);
    }
    if (s0 + 1 < s1) {
        const unsigned short* r = KV + (size_t)csrc[s0 + 1] * 256;
        krB = *(const unsigned int*)(r + lane * 2);
        vrB = *(const unsigned int*)(r + 128 + lane * 2);
    }
    for (int j = s0; j < s1; j += 2) {
        unsigned int ckA = krA, cvA = vrA, ckB = krB, cvB = vrB;
        bool hasB = (j + 1 < s1);
        if (j + 2 < s1) {
            const unsigned short* r = KV + (size_t)csrc[j + 2] * 256;
            krA = *(const unsigned int*)(r + lane * 2);
            vrA = *(const unsigned int*)(r + 128 + lane * 2);
        }
        if (j + 3 < s1) {
            const unsigned short* r = KV + (size_t)csrc[j + 3] * 256;
            krB = *(const unsigned int*)(r + lane * 2);
            vrB = *(const unsigned int*)(r + 128 + lane * 2);
        }
        float tA = q0 * bf2f_lo(ckA) + q1 * bf2f_hi(ckA);
        float tB = q0 * bf2f_lo(ckB) + q1 * bf2f_hi(ckB);
        tA += __shfl_xor(tA, 1);  tB += __shfl_xor(tB, 1);
        tA += __shfl_xor(tA, 2);  tB += __shfl_xor(tB, 2);
        tA += __shfl_xor(tA, 4);  tB += __shfl_xor(tB, 4);
        tA += __shfl_xor(tA, 8);  tB += __shfl_xor(tB, 8);
        tA = fminf(fmaxf(tA, -30.f), 30.f);
        float pA = __expf(tA);
        dA += pA;
        a0A += pA * bf2f_lo(cvA);
        a1A += pA * bf2f_hi(cvA);
        if (hasB) {
            tB = fminf(fmaxf(tB, -30.f), 30.f);
            float pB = __expf(tB);
            dB += pB;
            a0B += pB * bf2f_lo(cvB);
            a1B += pB * bf2f_hi(cvB);
        }
    }
    float r0 = 0.f, r1 = 0.f;
    if (s1 > s0) {
        float inv = 1.f / (dA + dB);
        r0 = (a0A + a0B) * inv;
        r1 = (a1A + a1B) * inv;
    }
    r0 = geluf(r0); r1 = geluf(r1);
    unsigned int o = (unsigned int)f2bf(r0) | ((unsigned int)f2bf(r1) << 16);
    *(unsigned int*)(out + (size_t)dst * 128 + lane * 2) = o;
}

// ---------------------------------------------------------------- output head with LDS binning (batch sorted)
__global__ __launch_bounds__(256) void k_head(
    const unsigned short* __restrict__ h2, const float* __restrict__ w2,
    const float* __restrict__ b2, const int* __restrict__ batch,
    int N, int G, float* __restrict__ gsum, float* __restrict__ gcnt) {
    __shared__ float sb[64][3];
    int t = threadIdx.x;
    for (int i = t; i < 192; i += 256) ((float*)sb)[i] = 0.f;
    __syncthreads();
    int base = blockIdx.x * 256;
    int bmin = batch[base];
    int node = base + t;
    if (node < N) {
        const uint4* hp = (const uint4*)(h2 + (size_t)node * 128);
        float l0 = b2[0], l1 = b2[1];
        #pragma unroll
        for (int j = 0; j < 16; ++j) {
            uint4 raw = hp[j];
            float e[8];
            e[0] = bf2f_lo(raw.x); e[1] = bf2f_hi(raw.x);
            e[2] = bf2f_lo(raw.y); e[3] = bf2f_hi(raw.y);
            e[4] = bf2f_lo(raw.z); e[5] = bf2f_hi(raw.z);
            e[6] = bf2f_lo(raw.w); e[7] = bf2f_hi(raw.w);
            int k = j * 8;
            #pragma unroll
            for (int q = 0; q < 8; ++q) {
                l0 += e[q] * w2[(k + q) * 2];
                l1 += e[q] * w2[(k + q) * 2 + 1];
            }
        }
        float m = fmaxf(l0, l1);
        float e0 = __expf(l0 - m), e1 = __expf(l1 - m);
        float inv = 1.f / (e0 + e1);
        float p0 = e0 * inv, p1 = e1 * inv;
        int b = batch[node];
        int rel = b - bmin;
        if (rel < 64) {
            atomicAdd(&sb[rel][0], p0);
            atomicAdd(&sb[rel][1], p1);
            atomicAdd(&sb[rel][2], 1.f);
        } else {
            atomicAdd(&gsum[b * 2 + 0], p0);
            atomicAdd(&gsum[b * 2 + 1], p1);
            atomicAdd(&gcnt[b], 1.f);
        }
    }
    __syncthreads();
    for (int i = t; i < 64; i += 256) {
        float c = sb[i][2];
        if (c != 0.f && bmin + i < G) {
            atomicAdd(&gsum[(bmin + i) * 2 + 0], sb[i][0]);
            atomicAdd(&gsum[(bmin + i) * 2 + 1], sb[i][1]);
            atomicAdd(&gcnt[bmin + i], c);
        }
    }
}
__global__ void k_finalize(const float* __restrict__ gsum, const float* __restrict__ gcnt,
                           float* __restrict__ out, int n) {
    int i = blockIdx.x * 256 + threadIdx.x;
    if (i < n) out[i] = gsum[i] / fmaxf(gcnt[i >> 1], 1.f);
}

// ---------------------------------------------------------------- host
extern "C" void kernel_launch(void* const* d_in, const int* in_sizes, int n_in,
                              void* d_out, int out_size, void* d_ws, size_t ws_size,
                              hipStream_t stream) {
    const float* x_var    = (const float*)d_in[0];
    const float* x_con    = (const float*)d_in[1];
    const float* mlp_in_w = (const float*)d_in[2];
    const float* mlp_in_b = (const float*)d_in[3];
    const float* mow0 = (const float*)d_in[4];
    const float* mob0 = (const float*)d_in[5];
    const float* mow1 = (const float*)d_in[6];
    const float* mob1 = (const float*)d_in[7];
    const float* mow2 = (const float*)d_in[8];
    const float* mob2 = (const float*)d_in[9];
    const float* k_w  = (const float*)d_in[10];
    const float* k_b  = (const float*)d_in[11];
    const float* q_w  = (const float*)d_in[12];
    const float* q_b  = (const float*)d_in[13];
    const float* v_w  = (const float*)d_in[14];
    const float* v_b  = (const float*)d_in[15];
    const float* a_w  = (const float*)d_in[16];
    const float* a_b  = (const float*)d_in[17];
    const float* skipP = (const float*)d_in[18];
    const float* a_rel = (const float*)d_in[19];
    const float* m_rel = (const float*)d_in[20];
    const float* p_rel = (const float*)d_in[21];
    const int* edge_vc = (const int*)d_in[22];
    const int* edge_cv = (const int*)d_in[23];
    const int* batch   = (const int*)d_in[24];

    const int Nv = in_sizes[0] / 128;
    const int Nc = in_sizes[1] / 128;
    const int E  = in_sizes[22] / 2;
    const int G  = out_size / 2;
    const int NT = Nv + Nc;

    // ---- workspace layout
    float* fbase = (float*)d_ws;
    size_t fo = 0;
    auto falloc = [&](size_t n) { float* p = fbase + fo; fo += n; return p; };
    float* Wkv  = falloc((size_t)4 * 128 * 256);
    float* Bkv  = falloc(4 * 256);
    float* gsum = falloc((size_t)G * 2);
    float* gcnt = falloc((size_t)G);

    unsigned short* bbase = (unsigned short*)(fbase + fo);
    size_t bo = 0;
    auto balloc = [&](size_t n) { unsigned short* p = bbase + bo; bo += n; return p; };
    unsigned short* Wswz = balloc((size_t)24 * 16384);
    unsigned short* curS = balloc((size_t)NT * 128);   // stacked [var | con] features
    unsigned short* Qs   = balloc((size_t)NT * 128);   // Q; aliased as agg output; MLP scratch
    unsigned short* KVs  = balloc((size_t)NT * 256);   // K'|V' stacked; MLP/head scratch

    int* ibase = (int*)(bbase + bo);
    size_t io = 0;
    auto ialloc = [&](size_t n) { int* p = ibase + io; io += n; return p; };
    int* offAll = ialloc((size_t)NT + 1);
    int* curAll = ialloc((size_t)NT + 1);
    int* srcAll = ialloc((size_t)E * 2);
    int* deg    = ialloc((size_t)NT);
    int* partials = ialloc(512);

    size_t need = (char*)(ibase + io) - (char*)d_ws;
    if (need > ws_size) return;

    const int eb  = (E + 255) / 256;
    const int nzb = (NT + 255) / 256;
    const int gNT = (NT + 63) / 64;
    const int gNv = (Nv + 63) / 64;

    // ---- combined CSR build ([var dsts | con dsts], srcs index stacked KVs)
    k_zero<<<nzb, 256, 0, stream>>>(deg, NT);
    k_hist2<<<dim3(eb, 2), 256, 0, stream>>>(edge_vc, edge_cv, E, deg, Nv);
    k_scan_block<<<nzb, 256, 0, stream>>>(deg, NT, offAll, partials);
    k_scan_partials<<<1, 512, 0, stream>>>(partials, nzb);
    k_scan_add<<<nzb, 256, 0, stream>>>(offAll, curAll, partials, NT);
    k_scatter2<<<dim3(eb, 2), 256, 0, stream>>>(edge_vc, edge_cv, E, curAll, Nv, srcAll);

    // ---- weight prep + swizzle
    k_prep<<<dim3((129 * 256 + 255) / 256, 4), 256, 0, stream>>>(
        k_w, k_b, v_w, v_b, a_rel, m_rel, p_rel, Wkv, Bkv);
    k_swz<<<dim3(64, 24), 256, 0, stream>>>(mlp_in_w, q_w, a_w, mow0, mow1, Wkv, Wswz);

    // ---- input MLPs, stacked var|con (units 0..2 / 3..5); scratch: Qs, KVs
    k_gemmf<<<gNT, 256, 0, stream>>>(
        x_var, x_con, Wswz, 0, 3, mlp_in_b + 0, mlp_in_b + 384, Qs, NT, Nv);
    k_gemmrs<true, false><<<gNT, 256, 0, stream>>>(
        Qs, Wswz, 1, 4, mlp_in_b + 128, mlp_in_b + 512, KVs, NT, Nv, nullptr, nullptr, nullptr);
    k_gemmrs<false, false><<<gNT, 256, 0, stream>>>(
        KVs, Wswz, 2, 5, mlp_in_b + 256, mlp_in_b + 640, curS, NT, Nv, nullptr, nullptr, nullptr);

    // ---- HGT layers: one QKV dispatch + one merged agg + one gated update per layer
    for (int l = 0; l < 2; ++l) {
        int lt0 = l * 2 + 0, lt1 = l * 2 + 1;
        k_qkv<<<gNT, 256, 0, stream>>>(curS, Wswz, q_b, Bkv, Qs, KVs, NT, Nv, l);
        k_agg<<<(NT + 3) / 4, 256, 0, stream>>>(Qs, KVs, offAll, srcAll, Qs, NT);
        k_gemmrs<false, true><<<gNT, 256, 0, stream>>>(
            Qs, Wswz, 10 + lt0, 10 + lt1, a_b + lt0 * 128, a_b + lt1 * 128,
            curS, NT, Nv, curS, skipP + lt0, skipP + lt1);
    }

    // ---- output head (var nodes = first Nv rows of curS)
    k_gemmrs<true, false><<<gNv, 256, 0, stream>>>(
        curS, Wswz, 14, 14, mob0, mob0, Qs, Nv, Nv, nullptr, nullptr, nullptr);
    k_gemmrs<true, false><<<gNv, 256, 0, stream>>>(
        Qs, Wswz, 15, 15, mob1, mob1, KVs, Nv, Nv, nullptr, nullptr, nullptr);
    k_zero<<<(G * 3 + 255) / 256, 256, 0, stream>>>((int*)gsum, G * 3);
    k_head<<<(Nv + 255) / 256, 256, 0, stream>>>(KVs, mow2, mob2, batch, Nv, G, gsum, gcnt);
    k_finalize<<<(G * 2 + 255) / 256, 256, 0, stream>>>(gsum, gcnt, (float*)d_out, G * 2);
}

// Round 6
// 565.040 us; speedup vs baseline: 2.1639x; 1.1656x over previous
//
#include <hip/hip_runtime.h>
#include <cstddef>
#include <cstdint>

typedef __attribute__((ext_vector_type(8))) short short8;
typedef __attribute__((ext_vector_type(4))) float float4v;

// ---------------------------------------------------------------- bf16 helpers
__device__ __forceinline__ float bf2f_lo(unsigned int u) {
    union { unsigned int i; float f; } v; v.i = u << 16; return v.f;
}
__device__ __forceinline__ float bf2f_hi(unsigned int u) {
    union { unsigned int i; float f; } v; v.i = u & 0xFFFF0000u; return v.f;
}
__device__ __forceinline__ float bf2f(unsigned int u16) {
    union { unsigned int i; float f; } v; v.i = u16 << 16; return v.f;
}
__device__ __forceinline__ unsigned short f2bf(float f) {
    union { float f; unsigned int i; } v; v.f = f;
    unsigned int x = v.i;
    unsigned int r = (x + 0x7FFFu + ((x >> 16) & 1u)) >> 16;
    return (unsigned short)r;
}
__device__ __forceinline__ float geluf(float x) {
    return 0.5f * x * (1.0f + erff(x * 0.70710678118654752f));
}
__device__ __forceinline__ void unpack8(const uint4& r, float* f) {
    f[0] = bf2f_lo(r.x); f[1] = bf2f_hi(r.x);
    f[2] = bf2f_lo(r.y); f[3] = bf2f_hi(r.y);
    f[4] = bf2f_lo(r.z); f[5] = bf2f_hi(r.z);
    f[6] = bf2f_lo(r.w); f[7] = bf2f_hi(r.w);
}

// ---------------------------------------------------------------- zero fill
__global__ void k_zero(int* __restrict__ p, int n) {
    int i = blockIdx.x * 256 + threadIdx.x;
    if (i < n) p[i] = 0;
}

// ---------------------------------------------------------------- prep: fold a_rel (+p_rel/sqrt D) / m_rel into K/V weights (fp32)
__global__ void k_prep(const float* __restrict__ kw, const float* __restrict__ kb,
                       const float* __restrict__ vw, const float* __restrict__ vb,
                       const float* __restrict__ arel, const float* __restrict__ mrel,
                       const float* __restrict__ prel,
                       float* __restrict__ Wkv, float* __restrict__ Bkv) {
    int lt = blockIdx.y;
    int tid = blockIdx.x * 256 + threadIdx.x;
    if (tid >= 129 * 256) return;
    int k = tid >> 8;
    int c = tid & 255;
    int sec = c >> 7, cc = c & 127, h = cc >> 5, e = cc & 31;
    const float* Wsrc = sec ? vw : kw;
    const float* Bsrc = sec ? vb : kb;
    const float* R    = sec ? mrel : arel;
    float scale = sec ? 1.0f : prel[lt * 4 + h] * 0.17677669529663687f;
    const float* rp = R + (size_t)(lt * 4 + h) * 1024 + e;
    const float* wp = (k < 128) ? (Wsrc + (size_t)lt * 16384 + (size_t)k * 128 + h * 32)
                                : (Bsrc + lt * 128 + h * 32);
    float s = 0.f;
    #pragma unroll 8
    for (int d = 0; d < 32; ++d) s += wp[d] * rp[(size_t)d * 32];
    s *= scale;
    if (k < 128) Wkv[(size_t)lt * 128 * 256 + (size_t)k * 256 + c] = s;
    else         Bkv[lt * 256 + c] = s;
}

// ---------------------------------------------------------------- swizzle weights into MFMA B-fragment order (bf16), 25 units
// out[((s*8+t)*64 + l)*8 + j] = W[k=s*32+(l>>4)*8+j][n=t*16+(l&15)]
__global__ void k_swz(const float* __restrict__ mlp_in_w, const float* __restrict__ q_w,
                      const float* __restrict__ a_w, const float* __restrict__ mow0,
                      const float* __restrict__ mow1, const float* __restrict__ mow2,
                      const float* __restrict__ Wkv, unsigned short* __restrict__ Wswz) {
    int idx = blockIdx.y;
    int f = blockIdx.x * 256 + threadIdx.x;
    if (f >= 16384) return;
    int j = f & 7, l = (f >> 3) & 63, t = (f >> 9) & 7, s = f >> 12;
    int k = s * 32 + (l >> 4) * 8 + j;
    int n = t * 16 + (l & 15);
    float val;
    if (idx < 6)        val = mlp_in_w[(size_t)idx * 16384 + (size_t)k * 128 + n];
    else if (idx < 10)  val = q_w[(size_t)(idx - 6) * 16384 + (size_t)k * 128 + n];
    else if (idx < 14)  val = a_w[(size_t)(idx - 10) * 16384 + (size_t)k * 128 + n];
    else if (idx == 14) val = mow0[(size_t)k * 128 + n];
    else if (idx == 15) val = mow1[(size_t)k * 128 + n];
    else if (idx < 24) { int u = idx - 16; val = Wkv[(size_t)(u >> 1) * 32768 + (size_t)k * 256 + (u & 1) * 128 + n]; }
    else                val = (n < 2) ? mow2[(size_t)k * 2 + n] : 0.f;   // padded w2 unit
    Wswz[(size_t)idx * 16384 + f] = f2bf(val);
}

// ---------------------------------------------------------------- MFMA helper
__device__ __forceinline__ void mfma32(const short8 av[4], const unsigned short* __restrict__ Bu,
                                       float4v acc[8]) {
    #pragma unroll
    for (int s = 0; s < 4; ++s)
        #pragma unroll
        for (int t = 0; t < 8; ++t) {
            short8 bv = *(const short8*)(Bu + (s * 8 + t) * 512);
            acc[t] = __builtin_amdgcn_mfma_f32_16x16x32_bf16(av[s], bv, acc[t], 0, 0, 0);
        }
}

// ---------------------------------------------------------------- fused 3-layer MLP (row-split var/con), LDS transpose between layers
__global__ __launch_bounds__(256) void k_mlp3(
    const float* __restrict__ Xa, const float* __restrict__ Xb,
    const unsigned short* __restrict__ Wswz, const float* __restrict__ mlp_in_b,
    unsigned short* __restrict__ C, int N, int Nsplit) {
    __shared__ unsigned short lds[4][16][136];
    const int lane = threadIdx.x & 63, wave = threadIdx.x >> 6;
    const int quad = lane >> 4, mrow = lane & 15;
    const int mbase = blockIdx.x * 64 + wave * 16;
    if (mbase >= N) return;
    const bool first = mbase < Nsplit;
    const float* bs = mlp_in_b + (first ? 0 : 384);
    const int ub = first ? 0 : 3;
    int r0 = mbase + mrow; if (r0 >= N) r0 = N - 1;
    const float* ap = ((r0 < Nsplit) ? (Xa + (size_t)r0 * 128)
                                     : (Xb + (size_t)(r0 - Nsplit) * 128)) + quad * 8;
    short8 av[4];
    #pragma unroll
    for (int s = 0; s < 4; ++s) {
        float4 f0 = *(const float4*)(ap + s * 32);
        float4 f1 = *(const float4*)(ap + s * 32 + 4);
        short8 a;
        a[0] = (short)f2bf(f0.x); a[1] = (short)f2bf(f0.y);
        a[2] = (short)f2bf(f0.z); a[3] = (short)f2bf(f0.w);
        a[4] = (short)f2bf(f1.x); a[5] = (short)f2bf(f1.y);
        a[6] = (short)f2bf(f1.z); a[7] = (short)f2bf(f1.w);
        av[s] = a;
    }
    #pragma unroll
    for (int layer = 0; layer < 3; ++layer) {
        const unsigned short* Bu = Wswz + (size_t)(ub + layer) * 16384 + lane * 8;
        float4v acc[8];
        #pragma unroll
        for (int t = 0; t < 8; ++t) acc[t] = (float4v){0.f, 0.f, 0.f, 0.f};
        mfma32(av, Bu, acc);
        const float* b = bs + layer * 128;
        if (layer < 2) {
            #pragma unroll
            for (int t = 0; t < 8; ++t) {
                int col = t * 16 + mrow;
                float bb = b[col];
                #pragma unroll
                for (int r = 0; r < 4; ++r)
                    lds[wave][quad * 4 + r][col] = f2bf(fmaxf(acc[t][r] + bb, 0.f));
            }
            #pragma unroll
            for (int s = 0; s < 4; ++s)
                av[s] = *(const short8*)&lds[wave][mrow][s * 32 + quad * 8];
        } else {
            #pragma unroll
            for (int t = 0; t < 8; ++t) {
                int col = t * 16 + mrow;
                float bb = b[col];
                #pragma unroll
                for (int r = 0; r < 4; ++r) {
                    int row = mbase + quad * 4 + r;
                    if (row < N) C[(size_t)row * 128 + col] = f2bf(acc[t][r] + bb);
                }
            }
        }
    }
}

// ---------------------------------------------------------------- a-lin gated update GEMM (stacked row-split)
__global__ __launch_bounds__(256) void k_alin(
    const unsigned short* __restrict__ A, const unsigned short* __restrict__ Wswz,
    int unitA, int unitB, const float* __restrict__ biasA, const float* __restrict__ biasB,
    unsigned short* __restrict__ C, int N, int Nsplit,
    const float* __restrict__ spA, const float* __restrict__ spB) {
    const int lane = threadIdx.x & 63, wave = threadIdx.x >> 6;
    const int quad = lane >> 4, mrow = lane & 15;
    const int mbase = blockIdx.x * 64 + wave * 16;
    if (mbase >= N) return;
    const bool first = mbase < Nsplit;
    const unsigned short* Bu = Wswz + (size_t)(first ? unitA : unitB) * 16384 + lane * 8;
    const float* bias = first ? biasA : biasB;
    int r0 = mbase + mrow; if (r0 >= N) r0 = N - 1;
    const unsigned short* ap = A + (size_t)r0 * 128 + quad * 8;
    short8 av[4];
    #pragma unroll
    for (int s = 0; s < 4; ++s) av[s] = *(const short8*)(ap + s * 32);
    float4v acc[8];
    #pragma unroll
    for (int t = 0; t < 8; ++t) acc[t] = (float4v){0.f, 0.f, 0.f, 0.f};
    mfma32(av, Bu, acc);
    const float* sp = first ? spA : spB;
    float g = 1.f / (1.f + __expf(-sp[0]));
    float og = 1.f - g;
    #pragma unroll
    for (int t = 0; t < 8; ++t) {
        int col = t * 16 + mrow;
        float b = bias[col];
        #pragma unroll
        for (int r = 0; r < 4; ++r) {
            int row = mbase + quad * 4 + r;
            if (row < N) {
                float v = g * (acc[t][r] + b) + og * bf2f(C[(size_t)row * 128 + col]);
                C[(size_t)row * 128 + col] = f2bf(v);
            }
        }
    }
}

// ---------------------------------------------------------------- fused Q + K' + V' per node, one dispatch per layer
__global__ __launch_bounds__(256) void k_qkv(
    const unsigned short* __restrict__ A, const unsigned short* __restrict__ Wswz,
    const float* __restrict__ q_b, const float* __restrict__ Bkv,
    unsigned short* __restrict__ Qs, unsigned short* __restrict__ KVs,
    int NT, int Nv, int l) {
    const int lane = threadIdx.x & 63, wave = threadIdx.x >> 6;
    const int quad = lane >> 4, mrow = lane & 15;
    const int mbase = blockIdx.x * 64 + wave * 16;
    if (mbase >= NT) return;
    const int lt = 2 * l + (mbase >= Nv ? 1 : 0);
    int r0 = mbase + mrow; if (r0 >= NT) r0 = NT - 1;
    const unsigned short* ap = A + (size_t)r0 * 128 + quad * 8;
    short8 av[4];
    #pragma unroll
    for (int s = 0; s < 4; ++s) av[s] = *(const short8*)(ap + s * 32);
    #pragma unroll
    for (int u = 0; u < 3; ++u) {
        int unit = (u == 0) ? (6 + lt) : (16 + lt * 2 + (u - 1));
        const unsigned short* Bu = Wswz + (size_t)unit * 16384 + lane * 8;
        float4v acc[8];
        #pragma unroll
        for (int t = 0; t < 8; ++t) acc[t] = (float4v){0.f, 0.f, 0.f, 0.f};
        mfma32(av, Bu, acc);
        const float* bias = (u == 0) ? (q_b + lt * 128) : (Bkv + lt * 256 + (u - 1) * 128);
        unsigned short* C = (u == 0) ? Qs : KVs;
        const int ldC = (u == 0) ? 128 : 256;
        const int cb = (u == 0) ? 0 : (u - 1) * 128;
        #pragma unroll
        for (int t = 0; t < 8; ++t) {
            int col = t * 16 + mrow;
            float b = bias[col];
            #pragma unroll
            for (int r = 0; r < 4; ++r) {
                int row = mbase + quad * 4 + r;
                if (row < NT) C[(size_t)row * ldC + cb + col] = f2bf(acc[t][r] + b);
            }
        }
    }
}

// ---------------------------------------------------------------- combined CSR build ([var dsts | con dsts])
__global__ void k_hist2(const int* __restrict__ evc, const int* __restrict__ ecv, int E,
                        int* __restrict__ deg, int Nv) {
    int e = blockIdx.x * 256 + threadIdx.x;
    if (e >= E) return;
    if (blockIdx.y == 0) atomicAdd(&deg[Nv + evc[E + e]], 1);
    else                 atomicAdd(&deg[ecv[E + e]], 1);
}
__global__ void k_scan_block(const int* __restrict__ deg, int n, int* __restrict__ off,
                             int* __restrict__ partials) {
    __shared__ int s[256];
    int i = blockIdx.x * 256 + threadIdx.x;
    s[threadIdx.x] = (i < n) ? deg[i] : 0;
    __syncthreads();
    for (int d = 1; d < 256; d <<= 1) {
        int t = (threadIdx.x >= d) ? s[threadIdx.x - d] : 0;
        __syncthreads();
        s[threadIdx.x] += t;
        __syncthreads();
    }
    if (i < n) off[i + 1] = s[threadIdx.x];
    if (threadIdx.x == 255) partials[blockIdx.x] = s[255];
}
__global__ void k_scan_partials(int* __restrict__ partials, int nb) {
    __shared__ int s[512];
    s[threadIdx.x] = (threadIdx.x < nb) ? partials[threadIdx.x] : 0;
    __syncthreads();
    for (int d = 1; d < 512; d <<= 1) {
        int t = (threadIdx.x >= d) ? s[threadIdx.x - d] : 0;
        __syncthreads();
        s[threadIdx.x] += t;
        __syncthreads();
    }
    if (threadIdx.x < nb) partials[threadIdx.x] = s[threadIdx.x];
}
__global__ void k_scan_add(int* __restrict__ off, int* __restrict__ cur,
                           const int* __restrict__ partials, int n) {
    int i = blockIdx.x * 256 + threadIdx.x;
    if (i == 0) { off[0] = 0; cur[0] = 0; }
    if (i < n) {
        int b = i >> 8;
        int v = off[i + 1] + ((b > 0) ? partials[b - 1] : 0);
        off[i + 1] = v;
        cur[i + 1] = v;
    }
}
__global__ void k_scatter2(const int* __restrict__ evc, const int* __restrict__ ecv, int E,
                           int* __restrict__ cur, int Nv, int* __restrict__ srcAll) {
    int e = blockIdx.x * 256 + threadIdx.x;
    if (e >= E) return;
    if (blockIdx.y == 0) {
        int d = Nv + evc[E + e];
        int pos = atomicAdd(&cur[d], 1);
        srcAll[pos] = evc[e];
    } else {
        int d = ecv[E + e];
        int pos = atomicAdd(&cur[d], 1);
        srcAll[pos] = Nv + ecv[e];
    }
}

// ---------------------------------------------------------------- fused attention: 4 edges/wave (16-lane groups), 8 ch/lane
// head = (lane&15)>>2 -> dot reduce = 2 shfl; no-max softmax (clamped); out aliases Q.
__global__ __launch_bounds__(256) void k_agg(
    const unsigned short* __restrict__ Q, const unsigned short* __restrict__ KV,
    const int* __restrict__ off, const int* __restrict__ csrc,
    unsigned short* __restrict__ out, int NT) {
    int dst = blockIdx.x * 4 + (threadIdx.x >> 6);
    int lane = threadIdx.x & 63;
    if (dst >= NT) return;
    const int g = lane >> 4, w = lane & 15;
    int s0 = off[dst], s1 = off[dst + 1];
    uint4 qr = *(const uint4*)(Q + (size_t)dst * 128 + w * 8);
    float q[8]; unpack8(qr, q);
    float acc[8] = {0.f, 0.f, 0.f, 0.f, 0.f, 0.f, 0.f, 0.f};
    float den = 0.f;
    int j = s0 + g;
    uint4 kr = {0, 0, 0, 0}, vr = {0, 0, 0, 0};
    bool have = j < s1;
    if (have) {
        const unsigned short* kv = KV + (size_t)csrc[j] * 256 + w * 8;
        kr = *(const uint4*)kv;
        vr = *(const uint4*)(kv + 128);
    }
    while (have) {
        int jn = j + 4;
        bool haveN = jn < s1;
        uint4 krn = kr, vrn = vr;
        if (haveN) {
            const unsigned short* kv = KV + (size_t)csrc[jn] * 256 + w * 8;
            krn = *(const uint4*)kv;
            vrn = *(const uint4*)(kv + 128);
        }
        float k[8]; unpack8(kr, k);
        float t = q[0] * k[0] + q[1] * k[1] + q[2] * k[2] + q[3] * k[3]
                + q[4] * k[4] + q[5] * k[5] + q[6] * k[6] + q[7] * k[7];
        t += __shfl_xor(t, 1);
        t += __shfl_xor(t, 2);
        t = fminf(fmaxf(t, -30.f), 30.f);
        float p = __expf(t);
        den += p;
        float v[8]; unpack8(vr, v);
        #pragma unroll
        for (int i = 0; i < 8; ++i) acc[i] += p * v[i];
        kr = krn; vr = vrn; j = jn; have = haveN;
    }
    den += __shfl_xor(den, 16);
    den += __shfl_xor(den, 32);
    #pragma unroll
    for (int i = 0; i < 8; ++i) {
        acc[i] += __shfl_xor(acc[i], 16);
        acc[i] += __shfl_xor(acc[i], 32);
    }
    if (g == 0) {
        float inv = (s1 > s0) ? 1.f / den : 0.f;
        uint4 o;
        unsigned int* op = (unsigned int*)&o;
        #pragma unroll
        for (int i = 0; i < 4; ++i) {
            float r0 = geluf(acc[2 * i] * inv);
            float r1 = geluf(acc[2 * i + 1] * inv);
            op[i] = (unsigned int)f2bf(r0) | ((unsigned int)f2bf(r1) << 16);
        }
        *(uint4*)(out + (size_t)dst * 128 + w * 8) = o;
    }
}

// ---------------------------------------------------------------- fused output head: h1 -> h2 -> logits (padded MFMA unit) -> softmax -> pool
__global__ __launch_bounds__(256) void k_headf(
    const unsigned short* __restrict__ A, const unsigned short* __restrict__ Wswz,
    const float* __restrict__ mob0, const float* __restrict__ mob1,
    const float* __restrict__ mob2, const int* __restrict__ batch,
    int N, int G, float* __restrict__ gsum, float* __restrict__ gcnt) {
    __shared__ unsigned short lds[4][16][136];
    __shared__ float sb[64][3];
    const int lane = threadIdx.x & 63, wave = threadIdx.x >> 6;
    const int quad = lane >> 4, mrow = lane & 15;
    const int tix = threadIdx.x;
    for (int i = tix; i < 192; i += 256) ((float*)sb)[i] = 0.f;
    __syncthreads();
    const int mbase = blockIdx.x * 64 + wave * 16;
    int bbase = blockIdx.x * 64; if (bbase >= N) bbase = N - 1;
    const int bmin = batch[bbase];
    if (mbase < N) {
        int r0 = mbase + mrow; if (r0 >= N) r0 = N - 1;
        const unsigned short* ap = A + (size_t)r0 * 128 + quad * 8;
        short8 av[4];
        #pragma unroll
        for (int s = 0; s < 4; ++s) av[s] = *(const short8*)(ap + s * 32);
        #pragma unroll
        for (int layer = 0; layer < 2; ++layer) {
            const unsigned short* Bu = Wswz + (size_t)(14 + layer) * 16384 + lane * 8;
            float4v acc[8];
            #pragma unroll
            for (int t = 0; t < 8; ++t) acc[t] = (float4v){0.f, 0.f, 0.f, 0.f};
            mfma32(av, Bu, acc);
            const float* b = layer ? mob1 : mob0;
            #pragma unroll
            for (int t = 0; t < 8; ++t) {
                int col = t * 16 + mrow;
                float bb = b[col];
                #pragma unroll
                for (int r = 0; r < 4; ++r)
                    lds[wave][quad * 4 + r][col] = f2bf(fmaxf(acc[t][r] + bb, 0.f));
            }
            #pragma unroll
            for (int s = 0; s < 4; ++s)
                av[s] = *(const short8*)&lds[wave][mrow][s * 32 + quad * 8];
        }
        // logits via padded unit 24, t=0 block only
        float4v lg = (float4v){0.f, 0.f, 0.f, 0.f};
        #pragma unroll
        for (int s = 0; s < 4; ++s) {
            short8 bv = *(const short8*)(Wswz + (size_t)24 * 16384 + (size_t)(s * 8) * 512 + lane * 8);
            lg = __builtin_amdgcn_mfma_f32_16x16x32_bf16(av[s], bv, lg, 0, 0, 0);
        }
        float4v lgo;
        #pragma unroll
        for (int r = 0; r < 4; ++r) lgo[r] = __shfl_xor(lg[r], 1);
        if (mrow == 0) {
            #pragma unroll
            for (int r = 0; r < 4; ++r) {
                int row = mbase + quad * 4 + r;
                if (row < N) {
                    float l0 = lg[r] + mob2[0];
                    float l1 = lgo[r] + mob2[1];
                    float mm = fmaxf(l0, l1);
                    float e0 = __expf(l0 - mm), e1 = __expf(l1 - mm);
                    float inv = 1.f / (e0 + e1);
                    int b = batch[row];
                    int rel = b - bmin;
                    if (rel >= 0 && rel < 64) {
                        atomicAdd(&sb[rel][0], e0 * inv);
                        atomicAdd(&sb[rel][1], e1 * inv);
                        atomicAdd(&sb[rel][2], 1.f);
                    } else {
                        atomicAdd(&gsum[b * 2 + 0], e0 * inv);
                        atomicAdd(&gsum[b * 2 + 1], e1 * inv);
                        atomicAdd(&gcnt[b], 1.f);
                    }
                }
            }
        }
    }
    __syncthreads();
    for (int i = tix; i < 64; i += 256) {
        float c = sb[i][2];
        if (c != 0.f && bmin + i < G) {
            atomicAdd(&gsum[(bmin + i) * 2 + 0], sb[i][0]);
            atomicAdd(&gsum[(bmin + i) * 2 + 1], sb[i][1]);
            atomicAdd(&gcnt[bmin + i], c);
        }
    }
}
__global__ void k_finalize(const float* __restrict__ gsum, const float* __restrict__ gcnt,
                           float* __restrict__ out, int n) {
    int i = blockIdx.x * 256 + threadIdx.x;
    if (i < n) out[i] = gsum[i] / fmaxf(gcnt[i >> 1], 1.f);
}

// ---------------------------------------------------------------- host
extern "C" void kernel_launch(void* const* d_in, const int* in_sizes, int n_in,
                              void* d_out, int out_size, void* d_ws, size_t ws_size,
                              hipStream_t stream) {
    const float* x_var    = (const float*)d_in[0];
    const float* x_con    = (const float*)d_in[1];
    const float* mlp_in_w = (const float*)d_in[2];
    const float* mlp_in_b = (const float*)d_in[3];
    const float* mow0 = (const float*)d_in[4];
    const float* mob0 = (const float*)d_in[5];
    const float* mow1 = (const float*)d_in[6];
    const float* mob1 = (const float*)d_in[7];
    const float* mow2 = (const float*)d_in[8];
    const float* mob2 = (const float*)d_in[9];
    const float* k_w  = (const float*)d_in[10];
    const float* k_b  = (const float*)d_in[11];
    const float* q_w  = (const float*)d_in[12];
    const float* q_b  = (const float*)d_in[13];
    const float* v_w  = (const float*)d_in[14];
    const float* v_b  = (const float*)d_in[15];
    const float* a_w  = (const float*)d_in[16];
    const float* a_b  = (const float*)d_in[17];
    const float* skipP = (const float*)d_in[18];
    const float* a_rel = (const float*)d_in[19];
    const float* m_rel = (const float*)d_in[20];
    const float* p_rel = (const float*)d_in[21];
    const int* edge_vc = (const int*)d_in[22];
    const int* edge_cv = (const int*)d_in[23];
    const int* batch   = (const int*)d_in[24];

    const int Nv = in_sizes[0] / 128;
    const int Nc = in_sizes[1] / 128;
    const int E  = in_sizes[22] / 2;
    const int G  = out_size / 2;
    const int NT = Nv + Nc;

    // ---- workspace layout
    float* fbase = (float*)d_ws;
    size_t fo = 0;
    auto falloc = [&](size_t n) { float* p = fbase + fo; fo += n; return p; };
    float* Wkv  = falloc((size_t)4 * 128 * 256);
    float* Bkv  = falloc(4 * 256);
    float* gsum = falloc((size_t)G * 2);
    float* gcnt = falloc((size_t)G);

    unsigned short* bbase = (unsigned short*)(fbase + fo);
    size_t bo = 0;
    auto balloc = [&](size_t n) { unsigned short* p = bbase + bo; bo += n; return p; };
    unsigned short* Wswz = balloc((size_t)25 * 16384);
    unsigned short* curS = balloc((size_t)NT * 128);
    unsigned short* Qs   = balloc((size_t)NT * 128);
    unsigned short* KVs  = balloc((size_t)NT * 256);

    int* ibase = (int*)(bbase + bo);
    size_t io = 0;
    auto ialloc = [&](size_t n) { int* p = ibase + io; io += n; return p; };
    int* offAll = ialloc((size_t)NT + 1);
    int* curAll = ialloc((size_t)NT + 1);
    int* srcAll = ialloc((size_t)E * 2);
    int* deg    = ialloc((size_t)NT);
    int* partials = ialloc(512);

    size_t need = (char*)(ibase + io) - (char*)d_ws;
    if (need > ws_size) return;

    const int eb   = (E + 255) / 256;
    const int nzb  = (NT + 255) / 256;
    const int gNT  = (NT + 63) / 64;
    const int gNv  = (Nv + 63) / 64;

    // ---- combined CSR build
    k_zero<<<nzb, 256, 0, stream>>>(deg, NT);
    k_hist2<<<dim3(eb, 2), 256, 0, stream>>>(edge_vc, edge_cv, E, deg, Nv);
    k_scan_block<<<nzb, 256, 0, stream>>>(deg, NT, offAll, partials);
    k_scan_partials<<<1, 512, 0, stream>>>(partials, nzb);
    k_scan_add<<<nzb, 256, 0, stream>>>(offAll, curAll, partials, NT);
    k_scatter2<<<dim3(eb, 2), 256, 0, stream>>>(edge_vc, edge_cv, E, curAll, Nv, srcAll);

    // ---- weight prep + swizzle (25 units)
    k_prep<<<dim3((129 * 256 + 255) / 256, 4), 256, 0, stream>>>(
        k_w, k_b, v_w, v_b, a_rel, m_rel, p_rel, Wkv, Bkv);
    k_swz<<<dim3(64, 25), 256, 0, stream>>>(mlp_in_w, q_w, a_w, mow0, mow1, mow2, Wkv, Wswz);

    // ---- fused input MLP (3 layers, one dispatch)
    k_mlp3<<<gNT, 256, 0, stream>>>(x_var, x_con, Wswz, mlp_in_b, curS, NT, Nv);

    // ---- HGT layers
    for (int l = 0; l < 2; ++l) {
        int lt0 = l * 2 + 0, lt1 = l * 2 + 1;
        k_qkv<<<gNT, 256, 0, stream>>>(curS, Wswz, q_b, Bkv, Qs, KVs, NT, Nv, l);
        k_agg<<<(NT + 3) / 4, 256, 0, stream>>>(Qs, KVs, offAll, srcAll, Qs, NT);
        k_alin<<<gNT, 256, 0, stream>>>(
            Qs, Wswz, 10 + lt0, 10 + lt1, a_b + lt0 * 128, a_b + lt1 * 128,
            curS, NT, Nv, skipP + lt0, skipP + lt1);
    }

    // ---- fused output head
    k_zero<<<(G * 3 + 255) / 256, 256, 0, stream>>>((int*)gsum, G * 3);
    k_headf<<<gNv, 256, 0, stream>>>(curS, Wswz, mob0, mob1, mob2, batch, Nv, G, gsum, gcnt);
    k_finalize<<<(G * 2 + 255) / 256, 256, 0, stream>>>(gsum, gcnt, (float*)d_out, G * 2);
}

// Round 7
// 525.424 us; speedup vs baseline: 2.3270x; 1.0754x over previous
//
#include <hip/hip_runtime.h>
#include <cstddef>
#include <cstdint>

typedef __attribute__((ext_vector_type(8))) short short8;
typedef __attribute__((ext_vector_type(4))) float float4v;
typedef __attribute__((ext_vector_type(2))) float float2v;
typedef __attribute__((ext_vector_type(2))) __bf16 bf162;

// ---------------------------------------------------------------- bf16 helpers
__device__ __forceinline__ float bf2f_lo(unsigned int u) {
    union { unsigned int i; float f; } v; v.i = u << 16; return v.f;
}
__device__ __forceinline__ float bf2f_hi(unsigned int u) {
    union { unsigned int i; float f; } v; v.i = u & 0xFFFF0000u; return v.f;
}
__device__ __forceinline__ unsigned short f2bf(float f) {
    union { float f; unsigned int i; } v; v.f = f;
    unsigned int x = v.i;
    unsigned int r = (x + 0x7FFFu + ((x >> 16) & 1u)) >> 16;
    return (unsigned short)r;
}
__device__ __forceinline__ float geluf(float x) {
    return 0.5f * x * (1.0f + erff(x * 0.70710678118654752f));
}
__device__ __forceinline__ float dot2bf(unsigned int a, unsigned int b, float c) {
#if defined(__has_builtin) && __has_builtin(__builtin_amdgcn_fdot2_f32_bf16)
    union U { unsigned int u; bf162 v; };
    U ua, ub; ua.u = a; ub.u = b;
    return __builtin_amdgcn_fdot2_f32_bf16(ua.v, ub.v, c, false);
#else
    return c + bf2f_lo(a) * bf2f_lo(b) + bf2f_hi(a) * bf2f_hi(b);
#endif
}
__device__ __forceinline__ unsigned int gate_pack(unsigned int nu, unsigned int ou,
                                                  float2v g2, float2v og2) {
    float2v n = {bf2f_lo(nu), bf2f_hi(nu)};
    float2v o = {bf2f_lo(ou), bf2f_hi(ou)};
    float2v r = n * g2 + o * og2;
    return (unsigned int)f2bf(r.x) | ((unsigned int)f2bf(r.y) << 16);
}

// ---------------------------------------------------------------- zero fill
__global__ void k_zero(int* __restrict__ p, int n) {
    int i = blockIdx.x * 256 + threadIdx.x;
    if (i < n) p[i] = 0;
}

// ---------------------------------------------------------------- swizzle weights into MFMA B-fragment order (bf16), 25 units
// Units 16..23 fold a_rel(+p_rel/sqrtD)/m_rel into k/v weights inline. y==25 computes Bkv bias fold.
__global__ void k_swz(const float* __restrict__ mlp_in_w, const float* __restrict__ q_w,
                      const float* __restrict__ a_w, const float* __restrict__ mow0,
                      const float* __restrict__ mow1, const float* __restrict__ mow2,
                      const float* __restrict__ kw, const float* __restrict__ kb,
                      const float* __restrict__ vw, const float* __restrict__ vb,
                      const float* __restrict__ arel, const float* __restrict__ mrel,
                      const float* __restrict__ prel,
                      unsigned short* __restrict__ Wswz, float* __restrict__ Bkv) {
    int idx = blockIdx.y;
    int f = blockIdx.x * 256 + threadIdx.x;
    if (idx == 25) {                      // bias fold for k'/v'
        if (f >= 1024) return;
        int lt = f >> 8, c = f & 255;
        int sec = c >> 7, cc = c & 127, h = cc >> 5, e = cc & 31;
        const float* B = sec ? vb : kb;
        const float* R = sec ? mrel : arel;
        float scale = sec ? 1.f : prel[lt * 4 + h] * 0.17677669529663687f;
        const float* rp = R + (size_t)(lt * 4 + h) * 1024 + e;
        const float* bp = B + lt * 128 + h * 32;
        float s = 0.f;
        #pragma unroll 8
        for (int d = 0; d < 32; ++d) s += bp[d] * rp[(size_t)d * 32];
        Bkv[lt * 256 + c] = s * scale;
        return;
    }
    if (f >= 16384) return;
    int j = f & 7, l = (f >> 3) & 63, t = (f >> 9) & 7, sb = f >> 12;
    int k = sb * 32 + (l >> 4) * 8 + j;
    int n = t * 16 + (l & 15);
    float val;
    if (idx < 6)        val = mlp_in_w[(size_t)idx * 16384 + (size_t)k * 128 + n];
    else if (idx < 10)  val = q_w[(size_t)(idx - 6) * 16384 + (size_t)k * 128 + n];
    else if (idx < 14)  val = a_w[(size_t)(idx - 10) * 16384 + (size_t)k * 128 + n];
    else if (idx == 14) val = mow0[(size_t)k * 128 + n];
    else if (idx == 15) val = mow1[(size_t)k * 128 + n];
    else if (idx < 24) {                  // folded k'/v' weights
        int u = idx - 16, lt = u >> 1, sec = u & 1;
        int h = n >> 5, e = n & 31;
        const float* W = sec ? vw : kw;
        const float* R = sec ? mrel : arel;
        float scale = sec ? 1.f : prel[lt * 4 + h] * 0.17677669529663687f;
        const float* rp = R + (size_t)(lt * 4 + h) * 1024 + e;
        const float* wp = W + (size_t)lt * 16384 + (size_t)k * 128 + h * 32;
        float s = 0.f;
        #pragma unroll 8
        for (int d = 0; d < 32; ++d) s += wp[d] * rp[(size_t)d * 32];
        val = s * scale;
    } else val = (n < 2) ? mow2[(size_t)k * 2 + n] : 0.f;   // padded w2 unit
    Wswz[(size_t)idx * 16384 + f] = f2bf(val);
}

// ---------------------------------------------------------------- MFMA helper
__device__ __forceinline__ void mfma32(const short8 av[4], const unsigned short* __restrict__ Bu,
                                       float4v acc[8]) {
    #pragma unroll
    for (int s = 0; s < 4; ++s)
        #pragma unroll
        for (int t = 0; t < 8; ++t) {
            short8 bv = *(const short8*)(Bu + (s * 8 + t) * 512);
            acc[t] = __builtin_amdgcn_mfma_f32_16x16x32_bf16(av[s], bv, acc[t], 0, 0, 0);
        }
}

// ---------------------------------------------------------------- fused input MLP (3 layers) + layer-0 QKV, one dispatch
__global__ __launch_bounds__(256) void k_mlp3qkv(
    const float* __restrict__ Xa, const float* __restrict__ Xb,
    const unsigned short* __restrict__ Wswz, const float* __restrict__ mlp_in_b,
    const float* __restrict__ q_b, const float* __restrict__ Bkv,
    unsigned short* __restrict__ curS, unsigned short* __restrict__ Qs,
    unsigned short* __restrict__ KVs, int NT, int Nv) {
    __shared__ unsigned short lds[4][16][136];
    const int lane = threadIdx.x & 63, wave = threadIdx.x >> 6;
    const int quad = lane >> 4, mrow = lane & 15;
    const int mbase = blockIdx.x * 64 + wave * 16;
    if (mbase >= NT) return;
    const bool first = mbase < Nv;
    const float* bs = mlp_in_b + (first ? 0 : 384);
    const int ub = first ? 0 : 3;
    const int lt = first ? 0 : 1;
    int r0 = mbase + mrow; if (r0 >= NT) r0 = NT - 1;
    const float* ap = ((r0 < Nv) ? (Xa + (size_t)r0 * 128)
                                 : (Xb + (size_t)(r0 - Nv) * 128)) + quad * 8;
    short8 av[4];
    #pragma unroll
    for (int s = 0; s < 4; ++s) {
        float4 f0 = *(const float4*)(ap + s * 32);
        float4 f1 = *(const float4*)(ap + s * 32 + 4);
        short8 a;
        a[0] = (short)f2bf(f0.x); a[1] = (short)f2bf(f0.y);
        a[2] = (short)f2bf(f0.z); a[3] = (short)f2bf(f0.w);
        a[4] = (short)f2bf(f1.x); a[5] = (short)f2bf(f1.y);
        a[6] = (short)f2bf(f1.z); a[7] = (short)f2bf(f1.w);
        av[s] = a;
    }
    #pragma unroll
    for (int layer = 0; layer < 3; ++layer) {
        const unsigned short* Bu = Wswz + (size_t)(ub + layer) * 16384 + lane * 8;
        float4v acc[8];
        #pragma unroll
        for (int t = 0; t < 8; ++t) acc[t] = (float4v){0.f, 0.f, 0.f, 0.f};
        mfma32(av, Bu, acc);
        const float* b = bs + layer * 128;
        bool relu = layer < 2;
        #pragma unroll
        for (int t = 0; t < 8; ++t) {
            int col = t * 16 + mrow;
            float bb = b[col];
            #pragma unroll
            for (int r = 0; r < 4; ++r) {
                float v = acc[t][r] + bb;
                if (relu) v = fmaxf(v, 0.f);
                lds[wave][quad * 4 + r][col] = f2bf(v);
            }
        }
        #pragma unroll
        for (int s = 0; s < 4; ++s)
            av[s] = *(const short8*)&lds[wave][mrow][s * 32 + quad * 8];
    }
    // store curS rows (vectorized)
    {
        int row = mbase + mrow;
        if (row < NT) {
            #pragma unroll
            for (int s = 0; s < 4; ++s)
                *(uint4*)(curS + (size_t)row * 128 + quad * 8 + s * 32) = *(uint4*)&av[s];
        }
    }
    // layer-0 QKV
    #pragma unroll
    for (int u = 0; u < 3; ++u) {
        int unit = (u == 0) ? (6 + lt) : (16 + lt * 2 + (u - 1));
        const unsigned short* Bu = Wswz + (size_t)unit * 16384 + lane * 8;
        float4v acc[8];
        #pragma unroll
        for (int t = 0; t < 8; ++t) acc[t] = (float4v){0.f, 0.f, 0.f, 0.f};
        mfma32(av, Bu, acc);
        const float* bias = (u == 0) ? (q_b + lt * 128) : (Bkv + lt * 256 + (u - 1) * 128);
        unsigned short* C = (u == 0) ? Qs : KVs;
        const int ldC = (u == 0) ? 128 : 256;
        const int cb = (u == 0) ? 0 : (u - 1) * 128;
        #pragma unroll
        for (int t = 0; t < 8; ++t) {
            int col = t * 16 + mrow;
            float b = bias[col];
            #pragma unroll
            for (int r = 0; r < 4; ++r) {
                int row = mbase + quad * 4 + r;
                if (row < NT) C[(size_t)row * ldC + cb + col] = f2bf(acc[t][r] + b);
            }
        }
    }
}

// ---------------------------------------------------------------- fused alin(l) gated update + QKV(l+1)
__global__ __launch_bounds__(256) void k_alinqkv(
    const unsigned short* __restrict__ Aagg, const unsigned short* __restrict__ Wswz,
    const float* __restrict__ a_b, const float* __restrict__ skipP,
    const float* __restrict__ q_b, const float* __restrict__ Bkv,
    unsigned short* __restrict__ curS, unsigned short* __restrict__ Qs,
    unsigned short* __restrict__ KVs, int NT, int Nv, int l) {
    __shared__ unsigned short lds[4][16][136];
    const int lane = threadIdx.x & 63, wave = threadIdx.x >> 6;
    const int quad = lane >> 4, mrow = lane & 15;
    const int mbase = blockIdx.x * 64 + wave * 16;
    if (mbase >= NT) return;
    const int type = (mbase >= Nv) ? 1 : 0;
    const int ltA = l * 2 + type;
    const int ltQ = (l + 1) * 2 + type;
    int r0 = mbase + mrow; if (r0 >= NT) r0 = NT - 1;
    const unsigned short* ap = Aagg + (size_t)r0 * 128 + quad * 8;
    short8 av[4];
    #pragma unroll
    for (int s = 0; s < 4; ++s) av[s] = *(const short8*)(ap + s * 32);
    // alin GEMM
    {
        const unsigned short* Bu = Wswz + (size_t)(10 + ltA) * 16384 + lane * 8;
        float4v acc[8];
        #pragma unroll
        for (int t = 0; t < 8; ++t) acc[t] = (float4v){0.f, 0.f, 0.f, 0.f};
        mfma32(av, Bu, acc);
        const float* b = a_b + ltA * 128;
        #pragma unroll
        for (int t = 0; t < 8; ++t) {
            int col = t * 16 + mrow;
            float bb = b[col];
            #pragma unroll
            for (int r = 0; r < 4; ++r)
                lds[wave][quad * 4 + r][col] = f2bf(acc[t][r] + bb);
        }
    }
    // gated update in row layout (vectorized), feed av + store curS
    {
        float gg = 1.f / (1.f + __expf(-skipP[ltA]));
        float2v g2 = {gg, gg}, og2 = {1.f - gg, 1.f - gg};
        int row = mbase + mrow;
        bool ok = row < NT;
        size_t rbase = (size_t)(ok ? row : 0) * 128;
        #pragma unroll
        for (int s = 0; s < 4; ++s) {
            short8 nv = *(const short8*)&lds[wave][mrow][s * 32 + quad * 8];
            uint4 nu = *(uint4*)&nv;
            uint4 ou = *(const uint4*)(curS + rbase + quad * 8 + s * 32);
            uint4 res;
            res.x = gate_pack(nu.x, ou.x, g2, og2);
            res.y = gate_pack(nu.y, ou.y, g2, og2);
            res.z = gate_pack(nu.z, ou.z, g2, og2);
            res.w = gate_pack(nu.w, ou.w, g2, og2);
            if (ok) *(uint4*)(curS + (size_t)row * 128 + quad * 8 + s * 32) = res;
            av[s] = *(short8*)&res;
        }
    }
    // QKV for layer l+1
    #pragma unroll
    for (int u = 0; u < 3; ++u) {
        int unit = (u == 0) ? (6 + ltQ) : (16 + ltQ * 2 + (u - 1));
        const unsigned short* Bu = Wswz + (size_t)unit * 16384 + lane * 8;
        float4v acc[8];
        #pragma unroll
        for (int t = 0; t < 8; ++t) acc[t] = (float4v){0.f, 0.f, 0.f, 0.f};
        mfma32(av, Bu, acc);
        const float* bias = (u == 0) ? (q_b + ltQ * 128) : (Bkv + ltQ * 256 + (u - 1) * 128);
        unsigned short* C = (u == 0) ? Qs : KVs;
        const int ldC = (u == 0) ? 128 : 256;
        const int cb = (u == 0) ? 0 : (u - 1) * 128;
        #pragma unroll
        for (int t = 0; t < 8; ++t) {
            int col = t * 16 + mrow;
            float b = bias[col];
            #pragma unroll
            for (int r = 0; r < 4; ++r) {
                int row = mbase + quad * 4 + r;
                if (row < NT) C[(size_t)row * ldC + cb + col] = f2bf(acc[t][r] + b);
            }
        }
    }
}

// ---------------------------------------------------------------- fused alin(last,var-only) + output head + pool
__global__ __launch_bounds__(256) void k_alinhead(
    const unsigned short* __restrict__ Aagg, const unsigned short* __restrict__ Wswz,
    const float* __restrict__ a_b, const float* __restrict__ skipP,
    const unsigned short* __restrict__ curS,
    const float* __restrict__ mob0, const float* __restrict__ mob1,
    const float* __restrict__ mob2, const int* __restrict__ batch,
    int N, int G, float* __restrict__ gsum, float* __restrict__ gcnt) {
    __shared__ unsigned short lds[4][16][136];
    __shared__ float sb[64][3];
    const int lane = threadIdx.x & 63, wave = threadIdx.x >> 6;
    const int quad = lane >> 4, mrow = lane & 15;
    const int tix = threadIdx.x;
    for (int i = tix; i < 192; i += 256) ((float*)sb)[i] = 0.f;
    __syncthreads();
    const int mbase = blockIdx.x * 64 + wave * 16;
    int bbase = blockIdx.x * 64; if (bbase >= N) bbase = N - 1;
    const int bmin = batch[bbase];
    if (mbase < N) {
        int r0 = mbase + mrow; if (r0 >= N) r0 = N - 1;
        const unsigned short* ap = Aagg + (size_t)r0 * 128 + quad * 8;
        short8 av[4];
        #pragma unroll
        for (int s = 0; s < 4; ++s) av[s] = *(const short8*)(ap + s * 32);
        // alin (lt = 2: layer 1, var)
        {
            const unsigned short* Bu = Wswz + (size_t)12 * 16384 + lane * 8;
            float4v acc[8];
            #pragma unroll
            for (int t = 0; t < 8; ++t) acc[t] = (float4v){0.f, 0.f, 0.f, 0.f};
            mfma32(av, Bu, acc);
            const float* b = a_b + 2 * 128;
            #pragma unroll
            for (int t = 0; t < 8; ++t) {
                int col = t * 16 + mrow;
                float bb = b[col];
                #pragma unroll
                for (int r = 0; r < 4; ++r)
                    lds[wave][quad * 4 + r][col] = f2bf(acc[t][r] + bb);
            }
        }
        {
            float gg = 1.f / (1.f + __expf(-skipP[2]));
            float2v g2 = {gg, gg}, og2 = {1.f - gg, 1.f - gg};
            size_t rbase = (size_t)r0 * 128;
            #pragma unroll
            for (int s = 0; s < 4; ++s) {
                short8 nv = *(const short8*)&lds[wave][mrow][s * 32 + quad * 8];
                uint4 nu = *(uint4*)&nv;
                uint4 ou = *(const uint4*)(curS + rbase + quad * 8 + s * 32);
                uint4 res;
                res.x = gate_pack(nu.x, ou.x, g2, og2);
                res.y = gate_pack(nu.y, ou.y, g2, og2);
                res.z = gate_pack(nu.z, ou.z, g2, og2);
                res.w = gate_pack(nu.w, ou.w, g2, og2);
                av[s] = *(short8*)&res;
            }
        }
        // head MLP: relu(unit14) -> relu(unit15) -> logits(unit24)
        #pragma unroll
        for (int layer = 0; layer < 2; ++layer) {
            const unsigned short* Bu = Wswz + (size_t)(14 + layer) * 16384 + lane * 8;
            float4v acc[8];
            #pragma unroll
            for (int t = 0; t < 8; ++t) acc[t] = (float4v){0.f, 0.f, 0.f, 0.f};
            mfma32(av, Bu, acc);
            const float* b = layer ? mob1 : mob0;
            #pragma unroll
            for (int t = 0; t < 8; ++t) {
                int col = t * 16 + mrow;
                float bb = b[col];
                #pragma unroll
                for (int r = 0; r < 4; ++r)
                    lds[wave][quad * 4 + r][col] = f2bf(fmaxf(acc[t][r] + bb, 0.f));
            }
            #pragma unroll
            for (int s = 0; s < 4; ++s)
                av[s] = *(const short8*)&lds[wave][mrow][s * 32 + quad * 8];
        }
        float4v lg = (float4v){0.f, 0.f, 0.f, 0.f};
        #pragma unroll
        for (int s = 0; s < 4; ++s) {
            short8 bv = *(const short8*)(Wswz + (size_t)24 * 16384 + (size_t)(s * 8) * 512 + lane * 8);
            lg = __builtin_amdgcn_mfma_f32_16x16x32_bf16(av[s], bv, lg, 0, 0, 0);
        }
        float4v lgo;
        #pragma unroll
        for (int r = 0; r < 4; ++r) lgo[r] = __shfl_xor(lg[r], 1);
        if (mrow == 0) {
            #pragma unroll
            for (int r = 0; r < 4; ++r) {
                int row = mbase + quad * 4 + r;
                if (row < N) {
                    float l0 = lg[r] + mob2[0];
                    float l1 = lgo[r] + mob2[1];
                    float mm = fmaxf(l0, l1);
                    float e0 = __expf(l0 - mm), e1 = __expf(l1 - mm);
                    float inv = 1.f / (e0 + e1);
                    int b = batch[row];
                    int rel = b - bmin;
                    if (rel >= 0 && rel < 64) {
                        atomicAdd(&sb[rel][0], e0 * inv);
                        atomicAdd(&sb[rel][1], e1 * inv);
                        atomicAdd(&sb[rel][2], 1.f);
                    } else {
                        atomicAdd(&gsum[b * 2 + 0], e0 * inv);
                        atomicAdd(&gsum[b * 2 + 1], e1 * inv);
                        atomicAdd(&gcnt[b], 1.f);
                    }
                }
            }
        }
    }
    __syncthreads();
    for (int i = tix; i < 64; i += 256) {
        float c = sb[i][2];
        if (c != 0.f && bmin + i < G) {
            atomicAdd(&gsum[(bmin + i) * 2 + 0], sb[i][0]);
            atomicAdd(&gsum[(bmin + i) * 2 + 1], sb[i][1]);
            atomicAdd(&gcnt[bmin + i], c);
        }
    }
}

// ---------------------------------------------------------------- combined CSR build
__global__ void k_hist2(const int* __restrict__ evc, const int* __restrict__ ecv, int E,
                        int* __restrict__ deg, int Nv) {
    int e = blockIdx.x * 256 + threadIdx.x;
    if (e >= E) return;
    if (blockIdx.y == 0) atomicAdd(&deg[Nv + evc[E + e]], 1);
    else                 atomicAdd(&deg[ecv[E + e]], 1);
}
__global__ void k_scan_block(const int* __restrict__ deg, int n, int* __restrict__ off,
                             int* __restrict__ partials) {
    __shared__ int s[256];
    int i = blockIdx.x * 256 + threadIdx.x;
    s[threadIdx.x] = (i < n) ? deg[i] : 0;
    __syncthreads();
    for (int d = 1; d < 256; d <<= 1) {
        int t = (threadIdx.x >= d) ? s[threadIdx.x - d] : 0;
        __syncthreads();
        s[threadIdx.x] += t;
        __syncthreads();
    }
    if (i < n) off[i + 1] = s[threadIdx.x];
    if (threadIdx.x == 255) partials[blockIdx.x] = s[255];
}
__global__ void k_scan_partials(int* __restrict__ partials, int nb) {
    __shared__ int s[512];
    s[threadIdx.x] = (threadIdx.x < nb) ? partials[threadIdx.x] : 0;
    __syncthreads();
    for (int d = 1; d < 512; d <<= 1) {
        int t = (threadIdx.x >= d) ? s[threadIdx.x - d] : 0;
        __syncthreads();
        s[threadIdx.x] += t;
        __syncthreads();
    }
    if (threadIdx.x < nb) partials[threadIdx.x] = s[threadIdx.x];
}
__global__ void k_scan_add(int* __restrict__ off, int* __restrict__ cur,
                           const int* __restrict__ partials, int n) {
    int i = blockIdx.x * 256 + threadIdx.x;
    if (i == 0) { off[0] = 0; cur[0] = 0; }
    if (i < n) {
        int b = i >> 8;
        int v = off[i + 1] + ((b > 0) ? partials[b - 1] : 0);
        off[i + 1] = v;
        cur[i + 1] = v;
    }
}
__global__ void k_scatter2(const int* __restrict__ evc, const int* __restrict__ ecv, int E,
                           int* __restrict__ cur, int Nv, int* __restrict__ srcAll) {
    int e = blockIdx.x * 256 + threadIdx.x;
    if (e >= E) return;
    if (blockIdx.y == 0) {
        int d = Nv + evc[E + e];
        int pos = atomicAdd(&cur[d], 1);
        srcAll[pos] = evc[e];
    } else {
        int d = ecv[E + e];
        int pos = atomicAdd(&cur[d], 1);
        srcAll[pos] = Nv + ecv[e];
    }
}

// ---------------------------------------------------------------- fused attention: 4 edges/wave, dot2 + pk_fma + distributed epilogue
__global__ __launch_bounds__(256) void k_agg(
    const unsigned short* __restrict__ Q, const unsigned short* __restrict__ KV,
    const int* __restrict__ off, const int* __restrict__ csrc,
    unsigned short* __restrict__ out, int NT) {
    int dst = blockIdx.x * 4 + (threadIdx.x >> 6);
    int lane = threadIdx.x & 63;
    if (dst >= NT) return;
    const int g = lane >> 4, w = lane & 15;
    int2 se = *(const int2*)(off + dst);
    int s0 = se.x, s1 = se.y;
    uint4 qr = *(const uint4*)(Q + (size_t)dst * 128 + w * 8);
    float2v a0 = {0.f, 0.f}, a1 = {0.f, 0.f}, a2 = {0.f, 0.f}, a3 = {0.f, 0.f};
    float den = 0.f;
    int j = s0 + g;
    uint4 kr = {0, 0, 0, 0}, vr = {0, 0, 0, 0};
    bool have = j < s1;
    if (have) {
        const unsigned short* kv = KV + (size_t)csrc[j] * 256 + w * 8;
        kr = *(const uint4*)kv;
        vr = *(const uint4*)(kv + 128);
    }
    while (have) {
        int jn = j + 4;
        bool haveN = jn < s1;
        uint4 krn = kr, vrn = vr;
        if (haveN) {
            const unsigned short* kv = KV + (size_t)csrc[jn] * 256 + w * 8;
            krn = *(const uint4*)kv;
            vrn = *(const uint4*)(kv + 128);
        }
        float t = dot2bf(kr.x, qr.x, 0.f);
        t = dot2bf(kr.y, qr.y, t);
        t = dot2bf(kr.z, qr.z, t);
        t = dot2bf(kr.w, qr.w, t);
        t += __shfl_xor(t, 1);
        t += __shfl_xor(t, 2);
        t = fminf(fmaxf(t, -30.f), 30.f);
        float p = __expf(t);
        den += p;
        float2v pv = {p, p};
        a0 += pv * (float2v){bf2f_lo(vr.x), bf2f_hi(vr.x)};
        a1 += pv * (float2v){bf2f_lo(vr.y), bf2f_hi(vr.y)};
        a2 += pv * (float2v){bf2f_lo(vr.z), bf2f_hi(vr.z)};
        a3 += pv * (float2v){bf2f_lo(vr.w), bf2f_hi(vr.w)};
        kr = krn; vr = vrn; j = jn; have = haveN;
    }
    // cross-group reduce (xor -> result in all lanes)
    den += __shfl_xor(den, 16); den += __shfl_xor(den, 32);
    a0.x += __shfl_xor(a0.x, 16); a0.x += __shfl_xor(a0.x, 32);
    a0.y += __shfl_xor(a0.y, 16); a0.y += __shfl_xor(a0.y, 32);
    a1.x += __shfl_xor(a1.x, 16); a1.x += __shfl_xor(a1.x, 32);
    a1.y += __shfl_xor(a1.y, 16); a1.y += __shfl_xor(a1.y, 32);
    a2.x += __shfl_xor(a2.x, 16); a2.x += __shfl_xor(a2.x, 32);
    a2.y += __shfl_xor(a2.y, 16); a2.y += __shfl_xor(a2.y, 32);
    a3.x += __shfl_xor(a3.x, 16); a3.x += __shfl_xor(a3.x, 32);
    a3.y += __shfl_xor(a3.y, 16); a3.y += __shfl_xor(a3.y, 32);
    float inv = (s1 > s0) ? 1.f / den : 0.f;
    float2v r = a0;
    if (g == 1) r = a1;
    if (g == 2) r = a2;
    if (g == 3) r = a3;
    float r0 = geluf(r.x * inv), r1 = geluf(r.y * inv);
    unsigned int o = (unsigned int)f2bf(r0) | ((unsigned int)f2bf(r1) << 16);
    *(unsigned int*)(out + (size_t)dst * 128 + w * 8 + g * 2) = o;
}

// ---------------------------------------------------------------- finalize
__global__ void k_finalize(const float* __restrict__ gsum, const float* __restrict__ gcnt,
                           float* __restrict__ out, int n) {
    int i = blockIdx.x * 256 + threadIdx.x;
    if (i < n) out[i] = gsum[i] / fmaxf(gcnt[i >> 1], 1.f);
}

// ---------------------------------------------------------------- host
extern "C" void kernel_launch(void* const* d_in, const int* in_sizes, int n_in,
                              void* d_out, int out_size, void* d_ws, size_t ws_size,
                              hipStream_t stream) {
    const float* x_var    = (const float*)d_in[0];
    const float* x_con    = (const float*)d_in[1];
    const float* mlp_in_w = (const float*)d_in[2];
    const float* mlp_in_b = (const float*)d_in[3];
    const float* mow0 = (const float*)d_in[4];
    const float* mob0 = (const float*)d_in[5];
    const float* mow1 = (const float*)d_in[6];
    const float* mob1 = (const float*)d_in[7];
    const float* mow2 = (const float*)d_in[8];
    const float* mob2 = (const float*)d_in[9];
    const float* k_w  = (const float*)d_in[10];
    const float* k_b  = (const float*)d_in[11];
    const float* q_w  = (const float*)d_in[12];
    const float* q_b  = (const float*)d_in[13];
    const float* v_w  = (const float*)d_in[14];
    const float* v_b  = (const float*)d_in[15];
    const float* a_w  = (const float*)d_in[16];
    const float* a_b  = (const float*)d_in[17];
    const float* skipP = (const float*)d_in[18];
    const float* a_rel = (const float*)d_in[19];
    const float* m_rel = (const float*)d_in[20];
    const float* p_rel = (const float*)d_in[21];
    const int* edge_vc = (const int*)d_in[22];
    const int* edge_cv = (const int*)d_in[23];
    const int* batch   = (const int*)d_in[24];

    const int Nv = in_sizes[0] / 128;
    const int Nc = in_sizes[1] / 128;
    const int E  = in_sizes[22] / 2;
    const int G  = out_size / 2;
    const int NT = Nv + Nc;

    // ---- workspace layout
    float* fbase = (float*)d_ws;
    size_t fo = 0;
    auto falloc = [&](size_t n) { float* p = fbase + fo; fo += n; return p; };
    float* Bkv  = falloc(4 * 256);
    float* gsum = falloc((size_t)G * 2);
    float* gcnt = falloc((size_t)G);

    unsigned short* bbase = (unsigned short*)(fbase + fo);
    size_t bo = 0;
    auto balloc = [&](size_t n) { unsigned short* p = bbase + bo; bo += n; return p; };
    unsigned short* Wswz = balloc((size_t)25 * 16384);
    unsigned short* curS = balloc((size_t)NT * 128);
    unsigned short* Qs   = balloc((size_t)NT * 128);
    unsigned short* KVs  = balloc((size_t)NT * 256);

    int* ibase = (int*)(bbase + bo);
    size_t io = 0;
    auto ialloc = [&](size_t n) { int* p = ibase + io; io += n; return p; };
    int* offAll = ialloc((size_t)NT + 1);
    int* curAll = ialloc((size_t)NT + 1);
    int* srcAll = ialloc((size_t)E * 2);
    int* deg    = ialloc((size_t)NT);
    int* partials = ialloc(512);

    size_t need = (char*)(ibase + io) - (char*)d_ws;
    if (need > ws_size) return;

    const int eb  = (E + 255) / 256;
    const int nzb = (NT + 255) / 256;
    const int gNT = (NT + 63) / 64;
    const int gNv = (Nv + 63) / 64;

    // ---- combined CSR build
    k_zero<<<nzb, 256, 0, stream>>>(deg, NT);
    k_hist2<<<dim3(eb, 2), 256, 0, stream>>>(edge_vc, edge_cv, E, deg, Nv);
    k_scan_block<<<nzb, 256, 0, stream>>>(deg, NT, offAll, partials);
    k_scan_partials<<<1, 512, 0, stream>>>(partials, nzb);
    k_scan_add<<<nzb, 256, 0, stream>>>(offAll, curAll, partials, NT);
    k_scatter2<<<dim3(eb, 2), 256, 0, stream>>>(edge_vc, edge_cv, E, curAll, Nv, srcAll);

    // ---- weight swizzle (prep folded in) + gsum zero
    k_swz<<<dim3(64, 26), 256, 0, stream>>>(mlp_in_w, q_w, a_w, mow0, mow1, mow2,
                                            k_w, k_b, v_w, v_b, a_rel, m_rel, p_rel,
                                            Wswz, Bkv);
    k_zero<<<(G * 3 + 255) / 256, 256, 0, stream>>>((int*)gsum, G * 3);

    // ---- fused pipeline
    k_mlp3qkv<<<gNT, 256, 0, stream>>>(x_var, x_con, Wswz, mlp_in_b, q_b, Bkv,
                                       curS, Qs, KVs, NT, Nv);
    k_agg<<<(NT + 3) / 4, 256, 0, stream>>>(Qs, KVs, offAll, srcAll, Qs, NT);
    k_alinqkv<<<gNT, 256, 0, stream>>>(Qs, Wswz, a_b, skipP, q_b, Bkv,
                                       curS, Qs, KVs, NT, Nv, 0);
    k_agg<<<(NT + 3) / 4, 256, 0, stream>>>(Qs, KVs, offAll, srcAll, Qs, NT);
    k_alinhead<<<gNv, 256, 0, stream>>>(Qs, Wswz, a_b, skipP, curS,
                                        mob0, mob1, mob2, batch, Nv, G, gsum, gcnt);
    k_finalize<<<(G * 2 + 255) / 256, 256, 0, stream>>>(gsum, gcnt, (float*)d_out, G * 2);
}